// Round 2
// baseline (257.853 us; speedup 1.0000x reference)
//
#include <hip/hip_runtime.h>
#include <math.h>

#define NB  32
#define NKC 128
#define DH  64
#define NEX 1024
#define G3  192
#define CHK 8      // i-rows per block
#define NCK 16     // sibling blocks per b

// ws layout (floats)
#define XOFF    0          // 32*64   = 2048
#define KCIOFF  2048       // 32*128  = 4096
#define DPOFF   6144       // 32*64*128 = 262144   [b][d][i] (transposed)
#define FLAGOFF 268288     // 64 ints: xflag[32], done[32]
#define FLAGBYTE (FLAGOFF * 4)

// LDS layout (floats) — phase B / phase C overlay
#define S_WHH   0       // B: whh68 (192*36=6912); fwA (64*68=4352)
#define S_DPT   0       // C: dpT 64*132 = 8448
#define S_UL    0       // C: ul68 4352
#define S_WIH36 0       // C: ugru wih 6912
#define S_WHH36 6912    // C: ugru whh 6912..13824
#define S_WIH   8448    // B: wih68 6912 (8448..15360)
#define S_DPTT  8448    // B: dpart transpose 64*9 = 576
#define S_FWB   8448    // C: fw68 4352 (8448..12800)
#define S_WJT   8448    // C: wjT 8*132 = 1056
#define S_WKT   12800   // C: wkT 8*68 = 544
#define S_HT    15360   // B: 512
#define S_PJS   15360   // C: 512 (HT dead)
#define S_DLT   15872   // B: 512
#define S_OUTJ  15872   // C: 512 (DLT dead)
#define S_XS    16384   // 64
#define S_KRED  16448   // B: 512
#define S_EPS   16448   // C: 512 (KRED dead)
#define S_KR2   16960   // 64
#define S_GIS   17024   // 192
#define S_BHH3  17216   // 192
#define S_KCIL  17408   // 16
#define S_NEWH  17424   // 512 (B epilogue -> C, never aliased)
#define S_KCIF  17936   // 128
#define S_KCJ   18064   // 16
#define S_BIH   18080   // 192
#define S_BHH   18272   // 192
#define SM_SIZE 18464   // 73856 B -> 2 blocks/CU (16 waves/CU)

__device__ __forceinline__ float sigf(float x) { return 1.0f / (1.0f + expf(-x)); }
__device__ __forceinline__ float dot4(float4 a, float4 b) {
    return fmaf(a.x, b.x, fmaf(a.y, b.y, fmaf(a.z, b.z, a.w * b.w)));
}

__global__ __launch_bounds__(512, 4) void kF(
    const float* __restrict__ h, const float* __restrict__ ex,
    const float* __restrict__ su, const float* __restrict__ ex_graph,
    const float* __restrict__ kc_gamma,
    const float* __restrict__ W_ex, const float* __restrict__ W_kc,
    const float* __restrict__ tgru_wih, const float* __restrict__ tgru_whh,
    const float* __restrict__ tgru_bih, const float* __restrict__ tgru_bhh,
    const float* __restrict__ fpart_w, const float* __restrict__ fpart_b,
    const float* __restrict__ ulin_w, const float* __restrict__ ulin_b,
    const float* __restrict__ ugru_wih, const float* __restrict__ ugru_whh,
    const float* __restrict__ ugru_bih, const float* __restrict__ ugru_bhh,
    float* __restrict__ ws, float* __restrict__ out)
{
    int t = threadIdx.x, wave = t >> 6, lane = t & 63;
    int b  = blockIdx.x >> 4;
    int ck = blockIdx.x & 15;
    int i0 = ck * CHK;

    __shared__ __align__(16) float sm[SM_SIZE];
    int* fx = (int*)(ws + FLAGOFF);   // x ready counters, per b (-> 16)
    int* fd = fx + 32;                // dpart/kci ready counters, per b (-> 16)

    // ---------------- Phase A: waves 0-3 each compute one x[b][ck*4+wave]
    if (wave < 4) {
        float sub = su[b];
        const float* exb = ex + (size_t)b * NEX;
        float er[16];
        #pragma unroll
        for (int i = 0; i < 16; ++i) er[i] = exb[lane + i * 64];
        int d = ck * 4 + wave;
        const float* wr = W_ex + (size_t)d * (2 * NEX);
        float a1 = 0.f, a2 = 0.f;
        #pragma unroll
        for (int i = 0; i < 16; ++i) {
            int k = lane + i * 64;
            a1 = fmaf(er[i], wr[k], a1);
            a2 = fmaf(er[i], wr[NEX + k], a2);
        }
        float v = sub * a1 + (1.0f - sub) * a2;
        #pragma unroll
        for (int off = 32; off; off >>= 1) v += __shfl_down(v, off, 64);
        if (lane == 0) ws[XOFF + b * DH + d] = v;
    }
    // kci partials (all waves): 8 cols x 64 k-groups of 16
    {
        int i = t & 7, ks = t >> 3, kb = ks * 16;
        const float* exb = ex + (size_t)b * NEX;
        const float* eg = ex_graph + i0 + i;
        float a0 = 0.f, a1 = 0.f;
        #pragma unroll
        for (int k = 0; k < 16; k += 2) {
            a0 = fmaf(exb[kb + k],     eg[(size_t)(kb + k) * NKC], a0);
            a1 = fmaf(exb[kb + k + 1], eg[(size_t)(kb + k + 1) * NKC], a1);
        }
        sm[S_KRED + t] = a0 + a1;
    }
    if (t < 128) {
        const float* hb = h + (size_t)(b * NKC + i0) * DH;
        *(float4*)&sm[S_HT + t * 4] = *(const float4*)&hb[t * 4];
    }
    if (t < G3) sm[S_BHH3 + t] = tgru_bhh[t];
    __syncthreads();
    if (t == 0)
        __hip_atomic_fetch_add(fx + b, 1, __ATOMIC_RELEASE, __HIP_MEMORY_SCOPE_AGENT);
    if (t < 64) {          // kci reduce stage 1 (wave 0 only, in-wave ordered)
        int i = t & 7, r = t >> 3;
        float s = 0.f;
        #pragma unroll
        for (int q = 0; q < 8; ++q) s += sm[S_KRED + (r * 8 + q) * 8 + i];
        sm[S_KR2 + t] = s;
    }
    if (t < 8) {
        float s = 0.f;
        #pragma unroll
        for (int q = 0; q < 8; ++q) s += sm[S_KR2 + q * 8 + t];
        sm[S_KCIL + t] = s;
        ws[KCIOFF + b * NKC + i0 + t] = s;
    }
    if (t == 0) {
        while (__hip_atomic_load(fx + b, __ATOMIC_ACQUIRE, __HIP_MEMORY_SCOPE_AGENT) < NCK)
            __builtin_amdgcn_s_sleep(1);
    }
    __syncthreads();
    if (t < DH) sm[S_XS + t] = ws[XOFF + b * DH + t];

    // ---------------- tgru main (1 row per wave)
    float giA = (t < G3) ? tgru_bih[t] : 0.f;
    float ar = sm[S_BHH3 + lane];
    float az = sm[S_BHH3 + 64 + lane];
    float an = sm[S_BHH3 + 128 + lane];
    for (int ch = 0; ch < 2; ++ch) {
        __syncthreads();
        for (int idx = t; idx < G3 * 8; idx += 512) {
            int row = idx >> 3, q = idx & 7;
            *(float4*)&sm[S_WHH + row * 36 + 4 * q] =
                *(const float4*)&tgru_whh[row * DH + ch * 32 + 4 * q];
            *(float4*)&sm[S_WIH + row * 36 + 4 * q] =
                *(const float4*)&tgru_wih[row * DH + ch * 32 + 4 * q];
        }
        __syncthreads();
        if (t < G3) {
            #pragma unroll
            for (int q = 0; q < 8; ++q)
                giA += dot4(*(float4*)&sm[S_WIH + t * 36 + 4 * q],
                            *(float4*)&sm[S_XS + ch * 32 + 4 * q]);
        }
        #pragma unroll
        for (int q = 0; q < 8; ++q) {
            int kb2 = ch * 32 + 4 * q;
            float4 hk = *(float4*)&sm[S_HT + wave * DH + kb2];   // bcast
            ar += dot4(*(float4*)&sm[S_WHH + lane * 36 + 4 * q], hk);
            az += dot4(*(float4*)&sm[S_WHH + (64 + lane) * 36 + 4 * q], hk);
            an += dot4(*(float4*)&sm[S_WHH + (128 + lane) * 36 + 4 * q], hk);
        }
    }
    if (t < G3) sm[S_GIS + t] = giA;
    __syncthreads();
    {
        float hval = sm[S_HT + wave * DH + lane];
        float r = sigf(sm[S_GIS + lane] + ar);
        float z = sigf(sm[S_GIS + 64 + lane] + az);
        float n = tanhf(sm[S_GIS + 128 + lane] + r * an);
        float th = (1.0f - z) * n + z * hval;
        float kv = sm[S_KCIL + wave];
        float nh = (1.0f - kv) * hval + kv * th;
        sm[S_NEWH + wave * DH + lane] = nh;        // stays in LDS for phase C
        sm[S_DLT + wave * DH + lane] = kv * (th - hval);
    }
    __syncthreads();
    // dpart = delta_h @ fpart_w[:, :64].T
    for (int idx = t; idx < 64 * 16; idx += 512) {
        int d = idx >> 4, q = idx & 15;
        *(float4*)&sm[S_WHH + d * 68 + 4 * q] = *(const float4*)&fpart_w[d * 128 + 4 * q];
    }
    __syncthreads();
    float acc = 0.f;
    #pragma unroll
    for (int q = 0; q < 16; ++q)
        acc += dot4(*(float4*)&sm[S_WHH + lane * 68 + 4 * q],
                    *(float4*)&sm[S_DLT + wave * DH + 4 * q]);   // bcast
    sm[S_DPTT + lane * 9 + wave] = acc;            // transpose, conflict-free
    __syncthreads();
    {
        int d = t >> 3, il = t & 7;
        ws[DPOFF + (size_t)b * 8192 + d * NKC + i0 + il] = sm[S_DPTT + d * 9 + il];
    }
    __syncthreads();
    if (t == 0)
        __hip_atomic_fetch_add(fd + b, 1, __ATOMIC_RELEASE, __HIP_MEMORY_SCOPE_AGENT);

    // ---------------- Phase C: prefetch + stage BEFORE the fd wait
    int ic = t >> 3, jc = t & 7;
    float g0  = kc_gamma[(size_t)ic * NKC + i0 + jc];
    float g1  = kc_gamma[(size_t)(ic + 64) * NKC + i0 + jc];
    float fpb = fpart_b[t & 63];
    float ulb = ulin_b[lane];
    for (int idx = t; idx < 64 * 16; idx += 512) {
        int d = idx >> 4, q = idx & 15;
        *(float4*)&sm[S_FWB + d * 68 + 4 * q] =
            *(const float4*)&fpart_w[d * 128 + 64 + 4 * q];
    }
    {   // W_kc transpose: 64 c x 8 jl
        int c = t >> 3, jl = t & 7;
        sm[S_WKT + jl * 68 + c] = W_kc[(size_t)c * NKC + i0 + jl];
    }
    if (t < G3) { sm[S_BIH + t] = ugru_bih[t]; sm[S_BHH + t] = ugru_bhh[t]; }
    if (t == 0) {
        while (__hip_atomic_load(fd + b, __ATOMIC_ACQUIRE, __HIP_MEMORY_SCOPE_AGENT) < NCK)
            __builtin_amdgcn_s_sleep(1);
    }
    __syncthreads();
    {   // stage full dpart [64][128] of b (stride 132) + kciF
        const float* dp = ws + DPOFF + (size_t)b * 8192;
        #pragma unroll
        for (int r = 0; r < 4; ++r) {
            int idx4 = t + r * 512;
            int d = idx4 >> 5, qi = idx4 & 31;
            *(float4*)&sm[S_DPT + d * 132 + 4 * qi] = *(const float4*)&dp[d * NKC + 4 * qi];
        }
    }
    if (t < NKC) sm[S_KCIF + t] = ws[KCIOFF + b * NKC + t];
    __syncthreads();
    {   // epart[jl,d]
        int jl = t >> 6, d = t & 63;
        float a = fpb;
        #pragma unroll
        for (int q = 0; q < 16; ++q)
            a += dot4(*(float4*)&sm[S_FWB + d * 68 + 4 * q],
                      *(float4*)&sm[S_WKT + jl * 68 + 4 * q]);
        sm[S_EPS + jl * DH + d] = a;
    }
    __syncthreads();   // fwB/wkT dead
    sm[S_WJT + jc * 132 + ic]      = sm[S_KCIF + ic]      * sigf(g0);
    sm[S_WJT + jc * 132 + ic + 64] = sm[S_KCIF + ic + 64] * sigf(g1);
    __syncthreads();
    if (t < 8) {
        float s = 0.f;
        #pragma unroll
        for (int qi = 0; qi < 32; ++qi) {
            float4 v = *(float4*)&sm[S_WJT + t * 132 + 4 * qi];
            s += v.x + v.y + v.z + v.w;
        }
        sm[S_KCJ + t] = s;
    }
    // partj: one jl per wave
    float ep = sm[S_EPS + wave * DH + lane], pa = 0.f;
    for (int qi = 0; qi < 32; ++qi) {
        float4 dv = *(float4*)&sm[S_DPT + lane * 132 + 4 * qi];
        float4 wv = *(float4*)&sm[S_WJT + wave * 132 + 4 * qi];   // bcast
        pa = fmaf(fmaxf(dv.x + ep, 0.f), wv.x, pa);
        pa = fmaf(fmaxf(dv.y + ep, 0.f), wv.y, pa);
        pa = fmaf(fmaxf(dv.z + ep, 0.f), wv.z, pa);
        pa = fmaf(fmaxf(dv.w + ep, 0.f), wv.w, pa);
    }
    sm[S_PJS + wave * DH + lane] = pa;
    __syncthreads();
    for (int idx = t; idx < 64 * 16; idx += 512) {     // ul68 (dpT dead)
        int d = idx >> 4, q = idx & 15;
        *(float4*)&sm[S_UL + d * 68 + 4 * q] = *(const float4*)&ulin_w[d * DH + 4 * q];
    }
    __syncthreads();
    float oa = ulb;
    #pragma unroll
    for (int q = 0; q < 16; ++q)
        oa += dot4(*(float4*)&sm[S_UL + lane * 68 + 4 * q],
                   *(float4*)&sm[S_PJS + wave * DH + 4 * q]);     // bcast
    sm[S_OUTJ + wave * DH + lane] = fmaxf(oa, 0.f);
    // ugru (k-chunked stride-36 weights)
    float gir = 0.f, giz = 0.f, gin = 0.f, ghr = 0.f, ghz = 0.f, ghn = 0.f;
    for (int ch = 0; ch < 2; ++ch) {
        __syncthreads();   // covers ul68/outj deps
        for (int idx = t; idx < G3 * 8; idx += 512) {
            int row = idx >> 3, q = idx & 7;
            *(float4*)&sm[S_WIH36 + row * 36 + 4 * q] =
                *(const float4*)&ugru_wih[row * DH + ch * 32 + 4 * q];
            *(float4*)&sm[S_WHH36 + row * 36 + 4 * q] =
                *(const float4*)&ugru_whh[row * DH + ch * 32 + 4 * q];
        }
        __syncthreads();
        #pragma unroll
        for (int q = 0; q < 8; ++q) {
            int kb2 = ch * 32 + 4 * q;
            float4 ov = *(float4*)&sm[S_OUTJ + wave * DH + kb2];   // bcast
            float4 nv = *(float4*)&sm[S_NEWH + wave * DH + kb2];   // bcast
            gir += dot4(*(float4*)&sm[S_WIH36 + lane * 36 + 4 * q], ov);
            giz += dot4(*(float4*)&sm[S_WIH36 + (64 + lane) * 36 + 4 * q], ov);
            gin += dot4(*(float4*)&sm[S_WIH36 + (128 + lane) * 36 + 4 * q], ov);
            ghr += dot4(*(float4*)&sm[S_WHH36 + lane * 36 + 4 * q], nv);
            ghz += dot4(*(float4*)&sm[S_WHH36 + (64 + lane) * 36 + 4 * q], nv);
            ghn += dot4(*(float4*)&sm[S_WHH36 + (128 + lane) * 36 + 4 * q], nv);
        }
    }
    {
        float r = sigf(gir + sm[S_BIH + lane] + ghr + sm[S_BHH + lane]);
        float z = sigf(giz + sm[S_BIH + 64 + lane] + ghz + sm[S_BHH + 64 + lane]);
        float n = tanhf(gin + sm[S_BIH + 128 + lane] +
                        r * (ghn + sm[S_BHH + 128 + lane]));
        float nh = sm[S_NEWH + wave * DH + lane];
        float uh = (1.0f - z) * n + z * nh;
        float kj = sm[S_KCJ + wave];
        out[(size_t)(b * NKC + i0 + wave) * DH + lane] = (1.0f - kj) * nh + kj * uh;
    }
}

extern "C" void kernel_launch(void* const* d_in, const int* in_sizes, int n_in,
                              void* d_out, int out_size, void* d_ws, size_t ws_size,
                              hipStream_t stream) {
    const float* h        = (const float*)d_in[0];
    const float* ex       = (const float*)d_in[1];
    const float* su       = (const float*)d_in[2];
    const float* ex_graph = (const float*)d_in[3];
    const float* kc_gamma = (const float*)d_in[4];
    const float* W_ex     = (const float*)d_in[5];
    const float* W_kc     = (const float*)d_in[6];
    const float* tgru_wih = (const float*)d_in[7];
    const float* tgru_whh = (const float*)d_in[8];
    const float* tgru_bih = (const float*)d_in[9];
    const float* tgru_bhh = (const float*)d_in[10];
    const float* fpart_w  = (const float*)d_in[11];
    const float* fpart_b  = (const float*)d_in[12];
    const float* ulin_w   = (const float*)d_in[13];
    const float* ulin_b   = (const float*)d_in[14];
    const float* ugru_wih = (const float*)d_in[15];
    const float* ugru_whh = (const float*)d_in[16];
    const float* ugru_bih = (const float*)d_in[17];
    const float* ugru_bhh = (const float*)d_in[18];
    float* ws  = (float*)d_ws;
    float* out = (float*)d_out;

    // zero the per-b flag counters (workspace is poisoned between runs)
    hipMemsetAsync((char*)d_ws + FLAGBYTE, 0, 64 * sizeof(int), stream);
    hipLaunchKernelGGL(kF, dim3(512), dim3(512), 0, stream,
                       h, ex, su, ex_graph, kc_gamma, W_ex, W_kc,
                       tgru_wih, tgru_whh, tgru_bih, tgru_bhh,
                       fpart_w, fpart_b, ulin_w, ulin_b,
                       ugru_wih, ugru_whh, ugru_bih, ugru_bhh,
                       ws, out);
}

// Round 3
// 184.488 us; speedup vs baseline: 1.3977x; 1.3977x over previous
//
#include <hip/hip_runtime.h>
#include <math.h>

#define NB  32
#define NKC 128
#define DH  64
#define NEX 1024
#define G3  192
#define CHK 8      // i-rows per block
#define NCK 16     // sibling blocks per b

// ws layout (floats)
#define XOFF    0          // 32*64   = 2048
#define KCIOFF  2048       // 32*128  = 4096
#define DPOFF   6144       // 32*64*128 = 262144   [b][d][i] (transposed)
#define FLAGOFF 268288     // 64 ints: xflag[32], done[32]
#define FLAGBYTE (FLAGOFF * 4)

// LDS layout (floats) — phase B / phase C overlay
#define S_WHH   0       // B: whh68 (192*36=6912); fwA (64*68=4352)
#define S_DPT   0       // C: dpT 64*132 = 8448
#define S_UL    0       // C: ul68 4352
#define S_WIH36 0       // C: ugru wih 6912
#define S_WHH36 6912    // C: ugru whh 6912..13824
#define S_WIH   8448    // B: wih68 6912 (8448..15360)
#define S_DPTT  8448    // B: dpart transpose 64*9 = 576
#define S_FWB   8448    // C: fw68 4352 (8448..12800)
#define S_WJT   8448    // C: wjT 8*132 = 1056
#define S_WKT   12800   // C: wkT 8*68 = 544
#define S_HT    15360   // B: 512
#define S_PJS   15360   // C: 512 (HT dead)
#define S_DLT   15872   // B: 512
#define S_OUTJ  15872   // C: 512 (DLT dead)
#define S_XS    16384   // 64
#define S_KRED  16448   // B: 512
#define S_EPS   16448   // C: 512 (KRED dead)
#define S_KR2   16960   // 64
#define S_GIS   17024   // 192
#define S_BHH3  17216   // 192
#define S_KCIL  17408   // 16
#define S_NEWH  17424   // 512 (B epilogue -> C, never aliased)
#define S_KCIF  17936   // 128
#define S_KCJ   18064   // 16
#define S_BIH   18080   // 192
#define S_BHH   18272   // 192
#define SM_SIZE 18464   // 73856 B -> 2 blocks/CU (16 waves/CU)

__device__ __forceinline__ float sigf(float x) { return 1.0f / (1.0f + expf(-x)); }
__device__ __forceinline__ float dot4(float4 a, float4 b) {
    return fmaf(a.x, b.x, fmaf(a.y, b.y, fmaf(a.z, b.z, a.w * b.w)));
}

// launch_bounds: empirically (this compiler) 2nd arg = min BLOCKS per CU.
// 2 blocks/CU * 8 waves = 16 waves/CU = 4 waves/SIMD -> VGPR cap 128, no spill.
__global__ __launch_bounds__(512, 2) void kF(
    const float* __restrict__ h, const float* __restrict__ ex,
    const float* __restrict__ su, const float* __restrict__ ex_graph,
    const float* __restrict__ kc_gamma,
    const float* __restrict__ W_ex, const float* __restrict__ W_kc,
    const float* __restrict__ tgru_wih, const float* __restrict__ tgru_whh,
    const float* __restrict__ tgru_bih, const float* __restrict__ tgru_bhh,
    const float* __restrict__ fpart_w, const float* __restrict__ fpart_b,
    const float* __restrict__ ulin_w, const float* __restrict__ ulin_b,
    const float* __restrict__ ugru_wih, const float* __restrict__ ugru_whh,
    const float* __restrict__ ugru_bih, const float* __restrict__ ugru_bhh,
    float* __restrict__ ws, float* __restrict__ out)
{
    int t = threadIdx.x, wave = t >> 6, lane = t & 63;
    int b  = blockIdx.x >> 4;
    int ck = blockIdx.x & 15;
    int i0 = ck * CHK;

    __shared__ __align__(16) float sm[SM_SIZE];
    int* fx = (int*)(ws + FLAGOFF);   // x ready counters, per b (-> 16)
    int* fd = fx + 32;                // dpart/kci ready counters, per b (-> 16)

    // ---------------- Phase A: waves 0-3 each compute one x[b][ck*4+wave]
    if (wave < 4) {
        float sub = su[b];
        const float* exb = ex + (size_t)b * NEX;
        float er[16];
        #pragma unroll
        for (int i = 0; i < 16; ++i) er[i] = exb[lane + i * 64];
        int d = ck * 4 + wave;
        const float* wr = W_ex + (size_t)d * (2 * NEX);
        float a1 = 0.f, a2 = 0.f;
        #pragma unroll
        for (int i = 0; i < 16; ++i) {
            int k = lane + i * 64;
            a1 = fmaf(er[i], wr[k], a1);
            a2 = fmaf(er[i], wr[NEX + k], a2);
        }
        float v = sub * a1 + (1.0f - sub) * a2;
        #pragma unroll
        for (int off = 32; off; off >>= 1) v += __shfl_down(v, off, 64);
        if (lane == 0) ws[XOFF + b * DH + d] = v;
    }
    // kci partials (all waves): 8 cols x 64 k-groups of 16
    {
        int i = t & 7, ks = t >> 3, kb = ks * 16;
        const float* exb = ex + (size_t)b * NEX;
        const float* eg = ex_graph + i0 + i;
        float a0 = 0.f, a1 = 0.f;
        #pragma unroll
        for (int k = 0; k < 16; k += 2) {
            a0 = fmaf(exb[kb + k],     eg[(size_t)(kb + k) * NKC], a0);
            a1 = fmaf(exb[kb + k + 1], eg[(size_t)(kb + k + 1) * NKC], a1);
        }
        sm[S_KRED + t] = a0 + a1;
    }
    if (t < 128) {
        const float* hb = h + (size_t)(b * NKC + i0) * DH;
        *(float4*)&sm[S_HT + t * 4] = *(const float4*)&hb[t * 4];
    }
    if (t < G3) sm[S_BHH3 + t] = tgru_bhh[t];
    __syncthreads();
    if (t == 0)
        __hip_atomic_fetch_add(fx + b, 1, __ATOMIC_RELEASE, __HIP_MEMORY_SCOPE_AGENT);
    if (t < 64) {          // kci reduce stage 1 (wave 0 only, in-wave ordered)
        int i = t & 7, r = t >> 3;
        float s = 0.f;
        #pragma unroll
        for (int q = 0; q < 8; ++q) s += sm[S_KRED + (r * 8 + q) * 8 + i];
        sm[S_KR2 + t] = s;
    }
    if (t < 8) {
        float s = 0.f;
        #pragma unroll
        for (int q = 0; q < 8; ++q) s += sm[S_KR2 + q * 8 + t];
        sm[S_KCIL + t] = s;
        ws[KCIOFF + b * NKC + i0 + t] = s;
    }
    if (t == 0) {
        while (__hip_atomic_load(fx + b, __ATOMIC_ACQUIRE, __HIP_MEMORY_SCOPE_AGENT) < NCK)
            __builtin_amdgcn_s_sleep(1);
    }
    __syncthreads();
    if (t < DH) sm[S_XS + t] = ws[XOFF + b * DH + t];

    // ---------------- tgru main (1 row per wave)
    float giA = (t < G3) ? tgru_bih[t] : 0.f;
    float ar = sm[S_BHH3 + lane];
    float az = sm[S_BHH3 + 64 + lane];
    float an = sm[S_BHH3 + 128 + lane];
    for (int ch = 0; ch < 2; ++ch) {
        __syncthreads();
        for (int idx = t; idx < G3 * 8; idx += 512) {
            int row = idx >> 3, q = idx & 7;
            *(float4*)&sm[S_WHH + row * 36 + 4 * q] =
                *(const float4*)&tgru_whh[row * DH + ch * 32 + 4 * q];
            *(float4*)&sm[S_WIH + row * 36 + 4 * q] =
                *(const float4*)&tgru_wih[row * DH + ch * 32 + 4 * q];
        }
        __syncthreads();
        if (t < G3) {
            #pragma unroll
            for (int q = 0; q < 8; ++q)
                giA += dot4(*(float4*)&sm[S_WIH + t * 36 + 4 * q],
                            *(float4*)&sm[S_XS + ch * 32 + 4 * q]);
        }
        #pragma unroll
        for (int q = 0; q < 8; ++q) {
            int kb2 = ch * 32 + 4 * q;
            float4 hk = *(float4*)&sm[S_HT + wave * DH + kb2];   // bcast
            ar += dot4(*(float4*)&sm[S_WHH + lane * 36 + 4 * q], hk);
            az += dot4(*(float4*)&sm[S_WHH + (64 + lane) * 36 + 4 * q], hk);
            an += dot4(*(float4*)&sm[S_WHH + (128 + lane) * 36 + 4 * q], hk);
        }
    }
    if (t < G3) sm[S_GIS + t] = giA;
    __syncthreads();
    {
        float hval = sm[S_HT + wave * DH + lane];
        float r = sigf(sm[S_GIS + lane] + ar);
        float z = sigf(sm[S_GIS + 64 + lane] + az);
        float n = tanhf(sm[S_GIS + 128 + lane] + r * an);
        float th = (1.0f - z) * n + z * hval;
        float kv = sm[S_KCIL + wave];
        float nh = (1.0f - kv) * hval + kv * th;
        sm[S_NEWH + wave * DH + lane] = nh;        // stays in LDS for phase C
        sm[S_DLT + wave * DH + lane] = kv * (th - hval);
    }
    __syncthreads();
    // dpart = delta_h @ fpart_w[:, :64].T
    for (int idx = t; idx < 64 * 16; idx += 512) {
        int d = idx >> 4, q = idx & 15;
        *(float4*)&sm[S_WHH + d * 68 + 4 * q] = *(const float4*)&fpart_w[d * 128 + 4 * q];
    }
    __syncthreads();
    float acc = 0.f;
    #pragma unroll
    for (int q = 0; q < 16; ++q)
        acc += dot4(*(float4*)&sm[S_WHH + lane * 68 + 4 * q],
                    *(float4*)&sm[S_DLT + wave * DH + 4 * q]);   // bcast
    sm[S_DPTT + lane * 9 + wave] = acc;            // transpose, conflict-free
    __syncthreads();
    {
        int d = t >> 3, il = t & 7;
        ws[DPOFF + (size_t)b * 8192 + d * NKC + i0 + il] = sm[S_DPTT + d * 9 + il];
    }
    __syncthreads();
    if (t == 0)
        __hip_atomic_fetch_add(fd + b, 1, __ATOMIC_RELEASE, __HIP_MEMORY_SCOPE_AGENT);

    // ---------------- Phase C: prefetch + stage BEFORE the fd wait
    int ic = t >> 3, jc = t & 7;
    float g0  = kc_gamma[(size_t)ic * NKC + i0 + jc];
    float g1  = kc_gamma[(size_t)(ic + 64) * NKC + i0 + jc];
    float fpb = fpart_b[t & 63];
    float ulb = ulin_b[lane];
    for (int idx = t; idx < 64 * 16; idx += 512) {
        int d = idx >> 4, q = idx & 15;
        *(float4*)&sm[S_FWB + d * 68 + 4 * q] =
            *(const float4*)&fpart_w[d * 128 + 64 + 4 * q];
    }
    {   // W_kc transpose: 64 c x 8 jl
        int c = t >> 3, jl = t & 7;
        sm[S_WKT + jl * 68 + c] = W_kc[(size_t)c * NKC + i0 + jl];
    }
    if (t < G3) { sm[S_BIH + t] = ugru_bih[t]; sm[S_BHH + t] = ugru_bhh[t]; }
    if (t == 0) {
        while (__hip_atomic_load(fd + b, __ATOMIC_ACQUIRE, __HIP_MEMORY_SCOPE_AGENT) < NCK)
            __builtin_amdgcn_s_sleep(1);
    }
    __syncthreads();
    {   // stage full dpart [64][128] of b (stride 132) + kciF
        const float* dp = ws + DPOFF + (size_t)b * 8192;
        #pragma unroll
        for (int r = 0; r < 4; ++r) {
            int idx4 = t + r * 512;
            int d = idx4 >> 5, qi = idx4 & 31;
            *(float4*)&sm[S_DPT + d * 132 + 4 * qi] = *(const float4*)&dp[d * NKC + 4 * qi];
        }
    }
    if (t < NKC) sm[S_KCIF + t] = ws[KCIOFF + b * NKC + t];
    __syncthreads();
    {   // epart[jl,d]
        int jl = t >> 6, d = t & 63;
        float a = fpb;
        #pragma unroll
        for (int q = 0; q < 16; ++q)
            a += dot4(*(float4*)&sm[S_FWB + d * 68 + 4 * q],
                      *(float4*)&sm[S_WKT + jl * 68 + 4 * q]);
        sm[S_EPS + jl * DH + d] = a;
    }
    __syncthreads();   // fwB/wkT dead
    sm[S_WJT + jc * 132 + ic]      = sm[S_KCIF + ic]      * sigf(g0);
    sm[S_WJT + jc * 132 + ic + 64] = sm[S_KCIF + ic + 64] * sigf(g1);
    __syncthreads();
    if (t < 8) {
        float s = 0.f;
        #pragma unroll
        for (int qi = 0; qi < 32; ++qi) {
            float4 v = *(float4*)&sm[S_WJT + t * 132 + 4 * qi];
            s += v.x + v.y + v.z + v.w;
        }
        sm[S_KCJ + t] = s;
    }
    // partj: one jl per wave
    float ep = sm[S_EPS + wave * DH + lane], pa = 0.f;
    for (int qi = 0; qi < 32; ++qi) {
        float4 dv = *(float4*)&sm[S_DPT + lane * 132 + 4 * qi];
        float4 wv = *(float4*)&sm[S_WJT + wave * 132 + 4 * qi];   // bcast
        pa = fmaf(fmaxf(dv.x + ep, 0.f), wv.x, pa);
        pa = fmaf(fmaxf(dv.y + ep, 0.f), wv.y, pa);
        pa = fmaf(fmaxf(dv.z + ep, 0.f), wv.z, pa);
        pa = fmaf(fmaxf(dv.w + ep, 0.f), wv.w, pa);
    }
    sm[S_PJS + wave * DH + lane] = pa;
    __syncthreads();
    for (int idx = t; idx < 64 * 16; idx += 512) {     // ul68 (dpT dead)
        int d = idx >> 4, q = idx & 15;
        *(float4*)&sm[S_UL + d * 68 + 4 * q] = *(const float4*)&ulin_w[d * DH + 4 * q];
    }
    __syncthreads();
    float oa = ulb;
    #pragma unroll
    for (int q = 0; q < 16; ++q)
        oa += dot4(*(float4*)&sm[S_UL + lane * 68 + 4 * q],
                   *(float4*)&sm[S_PJS + wave * DH + 4 * q]);     // bcast
    sm[S_OUTJ + wave * DH + lane] = fmaxf(oa, 0.f);
    // ugru (k-chunked stride-36 weights)
    float gir = 0.f, giz = 0.f, gin = 0.f, ghr = 0.f, ghz = 0.f, ghn = 0.f;
    for (int ch = 0; ch < 2; ++ch) {
        __syncthreads();   // covers ul68/outj deps
        for (int idx = t; idx < G3 * 8; idx += 512) {
            int row = idx >> 3, q = idx & 7;
            *(float4*)&sm[S_WIH36 + row * 36 + 4 * q] =
                *(const float4*)&ugru_wih[row * DH + ch * 32 + 4 * q];
            *(float4*)&sm[S_WHH36 + row * 36 + 4 * q] =
                *(const float4*)&ugru_whh[row * DH + ch * 32 + 4 * q];
        }
        __syncthreads();
        #pragma unroll
        for (int q = 0; q < 8; ++q) {
            int kb2 = ch * 32 + 4 * q;
            float4 ov = *(float4*)&sm[S_OUTJ + wave * DH + kb2];   // bcast
            float4 nv = *(float4*)&sm[S_NEWH + wave * DH + kb2];   // bcast
            gir += dot4(*(float4*)&sm[S_WIH36 + lane * 36 + 4 * q], ov);
            giz += dot4(*(float4*)&sm[S_WIH36 + (64 + lane) * 36 + 4 * q], ov);
            gin += dot4(*(float4*)&sm[S_WIH36 + (128 + lane) * 36 + 4 * q], ov);
            ghr += dot4(*(float4*)&sm[S_WHH36 + lane * 36 + 4 * q], nv);
            ghz += dot4(*(float4*)&sm[S_WHH36 + (64 + lane) * 36 + 4 * q], nv);
            ghn += dot4(*(float4*)&sm[S_WHH36 + (128 + lane) * 36 + 4 * q], nv);
        }
    }
    {
        float r = sigf(gir + sm[S_BIH + lane] + ghr + sm[S_BHH + lane]);
        float z = sigf(giz + sm[S_BIH + 64 + lane] + ghz + sm[S_BHH + 64 + lane]);
        float n = tanhf(gin + sm[S_BIH + 128 + lane] +
                        r * (ghn + sm[S_BHH + 128 + lane]));
        float nh = sm[S_NEWH + wave * DH + lane];
        float uh = (1.0f - z) * n + z * nh;
        float kj = sm[S_KCJ + wave];
        out[(size_t)(b * NKC + i0 + wave) * DH + lane] = (1.0f - kj) * nh + kj * uh;
    }
}

extern "C" void kernel_launch(void* const* d_in, const int* in_sizes, int n_in,
                              void* d_out, int out_size, void* d_ws, size_t ws_size,
                              hipStream_t stream) {
    const float* h        = (const float*)d_in[0];
    const float* ex       = (const float*)d_in[1];
    const float* su       = (const float*)d_in[2];
    const float* ex_graph = (const float*)d_in[3];
    const float* kc_gamma = (const float*)d_in[4];
    const float* W_ex     = (const float*)d_in[5];
    const float* W_kc     = (const float*)d_in[6];
    const float* tgru_wih = (const float*)d_in[7];
    const float* tgru_whh = (const float*)d_in[8];
    const float* tgru_bih = (const float*)d_in[9];
    const float* tgru_bhh = (const float*)d_in[10];
    const float* fpart_w  = (const float*)d_in[11];
    const float* fpart_b  = (const float*)d_in[12];
    const float* ulin_w   = (const float*)d_in[13];
    const float* ulin_b   = (const float*)d_in[14];
    const float* ugru_wih = (const float*)d_in[15];
    const float* ugru_whh = (const float*)d_in[16];
    const float* ugru_bih = (const float*)d_in[17];
    const float* ugru_bhh = (const float*)d_in[18];
    float* ws  = (float*)d_ws;
    float* out = (float*)d_out;

    // zero the per-b flag counters (workspace is poisoned between runs)
    hipMemsetAsync((char*)d_ws + FLAGBYTE, 0, 64 * sizeof(int), stream);
    hipLaunchKernelGGL(kF, dim3(512), dim3(512), 0, stream,
                       h, ex, su, ex_graph, kc_gamma, W_ex, W_kc,
                       tgru_wih, tgru_whh, tgru_bih, tgru_bhh,
                       fpart_w, fpart_b, ulin_w, ulin_b,
                       ugru_wih, ugru_whh, ugru_bih, ugru_bhh,
                       ws, out);
}

// Round 4
// 182.595 us; speedup vs baseline: 1.4122x; 1.0104x over previous
//
#include <hip/hip_runtime.h>
#include <math.h>

#define NB  32
#define NKC 128
#define DH  64
#define NEX 1024
#define G3  192
#define CHK 8      // i-rows per block
#define NCK 16     // sibling blocks per b

// ws layout (floats)
#define XOFF    0          // 32*64   = 2048
#define KCIOFF  2048       // 32*128  = 4096
#define DPOFF   6144       // 32*64*128 = 262144   [b][d][i] (transposed)
#define FLAGOFF 268288     // 64 ints: xflag[32], done[32]
#define FLAGBYTE (FLAGOFF * 4)

// LDS layout (floats) — phase B / phase C overlay
#define S_WHH   0       // B: whh68 (192*36=6912); fwA (64*68=4352)
#define S_DPT   0       // C: dpT 64*132 = 8448
#define S_UL    0       // C: ul68 4352
#define S_WIH36 0       // C: ugru wih 6912
#define S_WHH36 6912    // C: ugru whh 6912..13824
#define S_WIH   8448    // B: wih68 6912 (8448..15360)
#define S_DPTT  8448    // B: dpart transpose 64*9 = 576
#define S_FWB   8448    // C: fw68 4352 (8448..12800)
#define S_WJT   8448    // C: wjT 8*132 = 1056
#define S_WKT   12800   // C: wkT 8*68 = 544
#define S_HT    15360   // B: 512
#define S_PJS   15360   // C: 512 (HT dead)
#define S_DLT   15872   // B: 512
#define S_OUTJ  15872   // C: 512 (DLT dead)
#define S_XS    16384   // 64
#define S_KRED  16448   // B: 512
#define S_EPS   16448   // C: 512 (KRED dead)
#define S_KR2   16960   // 64
#define S_GIS   17024   // 192
#define S_BHH3  17216   // 192
#define S_KCIL  17408   // 16
#define S_NEWH  17424   // 512 (B epilogue -> C, never aliased)
#define S_KCIF  17936   // 128
#define S_KCJ   18064   // 16
#define S_BIH   18080   // 192
#define S_BHH   18272   // 192
#define SM_SIZE 18464   // 73856 B -> 2 blocks/CU (16 waves/CU)

__device__ __forceinline__ float sigf(float x) { return 1.0f / (1.0f + expf(-x)); }
__device__ __forceinline__ float dot4(float4 a, float4 b) {
    return fmaf(a.x, b.x, fmaf(a.y, b.y, fmaf(a.z, b.z, a.w * b.w)));
}

// launch_bounds 2nd arg: empirically min BLOCKS per CU on this compiler
// (r2: (512,4)->VGPR 64; r3: (512,2)->VGPR 128). Keep 2 blocks/CU -> cap 128.
// Unrolls are capped so natural demand stays UNDER 128 (r3 spilled 60MB at cap).
__global__ __launch_bounds__(512, 2) void kF(
    const float* __restrict__ h, const float* __restrict__ ex,
    const float* __restrict__ su, const float* __restrict__ ex_graph,
    const float* __restrict__ kc_gamma,
    const float* __restrict__ W_ex, const float* __restrict__ W_kc,
    const float* __restrict__ tgru_wih, const float* __restrict__ tgru_whh,
    const float* __restrict__ tgru_bih, const float* __restrict__ tgru_bhh,
    const float* __restrict__ fpart_w, const float* __restrict__ fpart_b,
    const float* __restrict__ ulin_w, const float* __restrict__ ulin_b,
    const float* __restrict__ ugru_wih, const float* __restrict__ ugru_whh,
    const float* __restrict__ ugru_bih, const float* __restrict__ ugru_bhh,
    float* __restrict__ ws, float* __restrict__ out)
{
    int t = threadIdx.x, wave = t >> 6, lane = t & 63;
    int b  = blockIdx.x >> 4;
    int ck = blockIdx.x & 15;
    int i0 = ck * CHK;

    __shared__ __align__(16) float sm[SM_SIZE];
    int* fx = (int*)(ws + FLAGOFF);   // x ready counters, per b (-> 16)
    int* fd = fx + 32;                // dpart/kci ready counters, per b (-> 16)

    // ---------------- Phase A: waves 0-3 each compute one x[b][ck*4+wave]
    if (wave < 4) {
        float sub = su[b];
        const float* exb = ex + (size_t)b * NEX;
        int d = ck * 4 + wave;
        const float* wr = W_ex + (size_t)d * (2 * NEX);
        float a1 = 0.f, a2 = 0.f;
        for (int hh = 0; hh < 2; ++hh) {          // stream ex in 8-chunks
            float er[8];
            #pragma unroll
            for (int i = 0; i < 8; ++i) er[i] = exb[lane + (hh * 8 + i) * 64];
            #pragma unroll
            for (int i = 0; i < 8; ++i) {
                int k = lane + (hh * 8 + i) * 64;
                a1 = fmaf(er[i], wr[k], a1);
                a2 = fmaf(er[i], wr[NEX + k], a2);
            }
        }
        float v = sub * a1 + (1.0f - sub) * a2;
        #pragma unroll
        for (int off = 32; off; off >>= 1) v += __shfl_down(v, off, 64);
        if (lane == 0) ws[XOFF + b * DH + d] = v;
    }
    // kci partials (all waves): 8 cols x 64 k-groups of 16
    {
        int i = t & 7, ks = t >> 3, kb = ks * 16;
        const float* exb = ex + (size_t)b * NEX;
        const float* eg = ex_graph + i0 + i;
        float a0 = 0.f, a1 = 0.f;
        #pragma unroll 4
        for (int k = 0; k < 16; k += 2) {
            a0 = fmaf(exb[kb + k],     eg[(size_t)(kb + k) * NKC], a0);
            a1 = fmaf(exb[kb + k + 1], eg[(size_t)(kb + k + 1) * NKC], a1);
        }
        sm[S_KRED + t] = a0 + a1;
    }
    if (t < 128) {
        const float* hb = h + (size_t)(b * NKC + i0) * DH;
        *(float4*)&sm[S_HT + t * 4] = *(const float4*)&hb[t * 4];
    }
    if (t < G3) sm[S_BHH3 + t] = tgru_bhh[t];
    __syncthreads();
    if (t == 0)
        __hip_atomic_fetch_add(fx + b, 1, __ATOMIC_RELEASE, __HIP_MEMORY_SCOPE_AGENT);
    if (t < 64) {          // kci reduce stage 1 (wave 0 only, in-wave ordered)
        int i = t & 7, r = t >> 3;
        float s = 0.f;
        #pragma unroll
        for (int q = 0; q < 8; ++q) s += sm[S_KRED + (r * 8 + q) * 8 + i];
        sm[S_KR2 + t] = s;
    }
    if (t < 8) {
        float s = 0.f;
        #pragma unroll
        for (int q = 0; q < 8; ++q) s += sm[S_KR2 + q * 8 + t];
        sm[S_KCIL + t] = s;
        ws[KCIOFF + b * NKC + i0 + t] = s;
    }
    if (t == 0) {
        while (__hip_atomic_load(fx + b, __ATOMIC_ACQUIRE, __HIP_MEMORY_SCOPE_AGENT) < NCK)
            __builtin_amdgcn_s_sleep(1);
    }
    __syncthreads();
    if (t < DH) sm[S_XS + t] = ws[XOFF + b * DH + t];

    // ---------------- tgru main (1 row per wave)
    float giA = (t < G3) ? tgru_bih[t] : 0.f;
    float ar = sm[S_BHH3 + lane];
    float az = sm[S_BHH3 + 64 + lane];
    float an = sm[S_BHH3 + 128 + lane];
    for (int ch = 0; ch < 2; ++ch) {
        __syncthreads();
        for (int idx = t; idx < G3 * 8; idx += 512) {
            int row = idx >> 3, q = idx & 7;
            *(float4*)&sm[S_WHH + row * 36 + 4 * q] =
                *(const float4*)&tgru_whh[row * DH + ch * 32 + 4 * q];
            *(float4*)&sm[S_WIH + row * 36 + 4 * q] =
                *(const float4*)&tgru_wih[row * DH + ch * 32 + 4 * q];
        }
        __syncthreads();
        if (t < G3) {
            #pragma unroll 4
            for (int q = 0; q < 8; ++q)
                giA += dot4(*(float4*)&sm[S_WIH + t * 36 + 4 * q],
                            *(float4*)&sm[S_XS + ch * 32 + 4 * q]);
        }
        #pragma unroll 4
        for (int q = 0; q < 8; ++q) {
            int kb2 = ch * 32 + 4 * q;
            float4 hk = *(float4*)&sm[S_HT + wave * DH + kb2];   // bcast
            ar += dot4(*(float4*)&sm[S_WHH + lane * 36 + 4 * q], hk);
            az += dot4(*(float4*)&sm[S_WHH + (64 + lane) * 36 + 4 * q], hk);
            an += dot4(*(float4*)&sm[S_WHH + (128 + lane) * 36 + 4 * q], hk);
        }
    }
    if (t < G3) sm[S_GIS + t] = giA;
    __syncthreads();
    {
        float hval = sm[S_HT + wave * DH + lane];
        float r = sigf(sm[S_GIS + lane] + ar);
        float z = sigf(sm[S_GIS + 64 + lane] + az);
        float n = tanhf(sm[S_GIS + 128 + lane] + r * an);
        float th = (1.0f - z) * n + z * hval;
        float kv = sm[S_KCIL + wave];
        float nh = (1.0f - kv) * hval + kv * th;
        sm[S_NEWH + wave * DH + lane] = nh;        // stays in LDS for phase C
        sm[S_DLT + wave * DH + lane] = kv * (th - hval);
    }
    __syncthreads();
    // dpart = delta_h @ fpart_w[:, :64].T
    for (int idx = t; idx < 64 * 16; idx += 512) {
        int d = idx >> 4, q = idx & 15;
        *(float4*)&sm[S_WHH + d * 68 + 4 * q] = *(const float4*)&fpart_w[d * 128 + 4 * q];
    }
    __syncthreads();
    float acc = 0.f;
    #pragma unroll 4
    for (int q = 0; q < 16; ++q)
        acc += dot4(*(float4*)&sm[S_WHH + lane * 68 + 4 * q],
                    *(float4*)&sm[S_DLT + wave * DH + 4 * q]);   // bcast
    sm[S_DPTT + lane * 9 + wave] = acc;            // transpose, conflict-free
    __syncthreads();
    {
        int d = t >> 3, il = t & 7;
        ws[DPOFF + (size_t)b * 8192 + d * NKC + i0 + il] = sm[S_DPTT + d * 9 + il];
    }
    __syncthreads();
    if (t == 0)
        __hip_atomic_fetch_add(fd + b, 1, __ATOMIC_RELEASE, __HIP_MEMORY_SCOPE_AGENT);

    // ---------------- Phase C: stage b-independent weights BEFORE the fd wait
    int ic = t >> 3, jc = t & 7;
    float fpb = fpart_b[t & 63];
    float ulb = ulin_b[lane];
    for (int idx = t; idx < 64 * 16; idx += 512) {
        int d = idx >> 4, q = idx & 15;
        *(float4*)&sm[S_FWB + d * 68 + 4 * q] =
            *(const float4*)&fpart_w[d * 128 + 64 + 4 * q];
    }
    {   // W_kc transpose: 64 c x 8 jl
        int c = t >> 3, jl = t & 7;
        sm[S_WKT + jl * 68 + c] = W_kc[(size_t)c * NKC + i0 + jl];
    }
    if (t < G3) { sm[S_BIH + t] = ugru_bih[t]; sm[S_BHH + t] = ugru_bhh[t]; }
    if (t == 0) {
        while (__hip_atomic_load(fd + b, __ATOMIC_ACQUIRE, __HIP_MEMORY_SCOPE_AGENT) < NCK)
            __builtin_amdgcn_s_sleep(1);
    }
    __syncthreads();
    // kc_gamma prefetch HERE (short live range, overlaps dpT staging batch)
    float g0  = kc_gamma[(size_t)ic * NKC + i0 + jc];
    float g1  = kc_gamma[(size_t)(ic + 64) * NKC + i0 + jc];
    {   // stage full dpart [64][128] of b (stride 132) + kciF
        const float* dp = ws + DPOFF + (size_t)b * 8192;
        #pragma unroll 4
        for (int r = 0; r < 4; ++r) {
            int idx4 = t + r * 512;
            int d = idx4 >> 5, qi = idx4 & 31;
            *(float4*)&sm[S_DPT + d * 132 + 4 * qi] = *(const float4*)&dp[d * NKC + 4 * qi];
        }
    }
    if (t < NKC) sm[S_KCIF + t] = ws[KCIOFF + b * NKC + t];
    __syncthreads();
    {   // epart[jl,d]
        int jl = t >> 6, d = t & 63;
        float a = fpb;
        #pragma unroll 8
        for (int q = 0; q < 16; ++q)
            a += dot4(*(float4*)&sm[S_FWB + d * 68 + 4 * q],
                      *(float4*)&sm[S_WKT + jl * 68 + 4 * q]);
        sm[S_EPS + jl * DH + d] = a;
    }
    __syncthreads();   // fwB/wkT dead
    sm[S_WJT + jc * 132 + ic]      = sm[S_KCIF + ic]      * sigf(g0);
    sm[S_WJT + jc * 132 + ic + 64] = sm[S_KCIF + ic + 64] * sigf(g1);
    __syncthreads();
    if (t < 8) {
        float s = 0.f;
        #pragma unroll 8
        for (int qi = 0; qi < 32; ++qi) {
            float4 v = *(float4*)&sm[S_WJT + t * 132 + 4 * qi];
            s += v.x + v.y + v.z + v.w;
        }
        sm[S_KCJ + t] = s;
    }
    // partj: one jl per wave
    float ep = sm[S_EPS + wave * DH + lane], pa = 0.f;
    #pragma unroll 4
    for (int qi = 0; qi < 32; ++qi) {
        float4 dv = *(float4*)&sm[S_DPT + lane * 132 + 4 * qi];
        float4 wv = *(float4*)&sm[S_WJT + wave * 132 + 4 * qi];   // bcast
        pa = fmaf(fmaxf(dv.x + ep, 0.f), wv.x, pa);
        pa = fmaf(fmaxf(dv.y + ep, 0.f), wv.y, pa);
        pa = fmaf(fmaxf(dv.z + ep, 0.f), wv.z, pa);
        pa = fmaf(fmaxf(dv.w + ep, 0.f), wv.w, pa);
    }
    sm[S_PJS + wave * DH + lane] = pa;
    __syncthreads();
    for (int idx = t; idx < 64 * 16; idx += 512) {     // ul68 (dpT dead)
        int d = idx >> 4, q = idx & 15;
        *(float4*)&sm[S_UL + d * 68 + 4 * q] = *(const float4*)&ulin_w[d * DH + 4 * q];
    }
    __syncthreads();
    float oa = ulb;
    #pragma unroll 8
    for (int q = 0; q < 16; ++q)
        oa += dot4(*(float4*)&sm[S_UL + lane * 68 + 4 * q],
                   *(float4*)&sm[S_PJS + wave * DH + 4 * q]);     // bcast
    sm[S_OUTJ + wave * DH + lane] = fmaxf(oa, 0.f);
    // ugru (k-chunked stride-36 weights)
    float gir = 0.f, giz = 0.f, gin = 0.f, ghr = 0.f, ghz = 0.f, ghn = 0.f;
    for (int ch = 0; ch < 2; ++ch) {
        __syncthreads();   // covers ul68/outj deps
        for (int idx = t; idx < G3 * 8; idx += 512) {
            int row = idx >> 3, q = idx & 7;
            *(float4*)&sm[S_WIH36 + row * 36 + 4 * q] =
                *(const float4*)&ugru_wih[row * DH + ch * 32 + 4 * q];
            *(float4*)&sm[S_WHH36 + row * 36 + 4 * q] =
                *(const float4*)&ugru_whh[row * DH + ch * 32 + 4 * q];
        }
        __syncthreads();
        #pragma unroll 2
        for (int q = 0; q < 8; ++q) {
            int kb2 = ch * 32 + 4 * q;
            float4 ov = *(float4*)&sm[S_OUTJ + wave * DH + kb2];   // bcast
            float4 nv = *(float4*)&sm[S_NEWH + wave * DH + kb2];   // bcast
            gir += dot4(*(float4*)&sm[S_WIH36 + lane * 36 + 4 * q], ov);
            giz += dot4(*(float4*)&sm[S_WIH36 + (64 + lane) * 36 + 4 * q], ov);
            gin += dot4(*(float4*)&sm[S_WIH36 + (128 + lane) * 36 + 4 * q], ov);
            ghr += dot4(*(float4*)&sm[S_WHH36 + lane * 36 + 4 * q], nv);
            ghz += dot4(*(float4*)&sm[S_WHH36 + (64 + lane) * 36 + 4 * q], nv);
            ghn += dot4(*(float4*)&sm[S_WHH36 + (128 + lane) * 36 + 4 * q], nv);
        }
    }
    {
        float r = sigf(gir + sm[S_BIH + lane] + ghr + sm[S_BHH + lane]);
        float z = sigf(giz + sm[S_BIH + 64 + lane] + ghz + sm[S_BHH + 64 + lane]);
        float n = tanhf(gin + sm[S_BIH + 128 + lane] +
                        r * (ghn + sm[S_BHH + 128 + lane]));
        float nh = sm[S_NEWH + wave * DH + lane];
        float uh = (1.0f - z) * n + z * nh;
        float kj = sm[S_KCJ + wave];
        out[(size_t)(b * NKC + i0 + wave) * DH + lane] = (1.0f - kj) * nh + kj * uh;
    }
}

extern "C" void kernel_launch(void* const* d_in, const int* in_sizes, int n_in,
                              void* d_out, int out_size, void* d_ws, size_t ws_size,
                              hipStream_t stream) {
    const float* h        = (const float*)d_in[0];
    const float* ex       = (const float*)d_in[1];
    const float* su       = (const float*)d_in[2];
    const float* ex_graph = (const float*)d_in[3];
    const float* kc_gamma = (const float*)d_in[4];
    const float* W_ex     = (const float*)d_in[5];
    const float* W_kc     = (const float*)d_in[6];
    const float* tgru_wih = (const float*)d_in[7];
    const float* tgru_whh = (const float*)d_in[8];
    const float* tgru_bih = (const float*)d_in[9];
    const float* tgru_bhh = (const float*)d_in[10];
    const float* fpart_w  = (const float*)d_in[11];
    const float* fpart_b  = (const float*)d_in[12];
    const float* ulin_w   = (const float*)d_in[13];
    const float* ulin_b   = (const float*)d_in[14];
    const float* ugru_wih = (const float*)d_in[15];
    const float* ugru_whh = (const float*)d_in[16];
    const float* ugru_bih = (const float*)d_in[17];
    const float* ugru_bhh = (const float*)d_in[18];
    float* ws  = (float*)d_ws;
    float* out = (float*)d_out;

    // zero the per-b flag counters (workspace is poisoned between runs)
    hipMemsetAsync((char*)d_ws + FLAGBYTE, 0, 64 * sizeof(int), stream);
    hipLaunchKernelGGL(kF, dim3(512), dim3(512), 0, stream,
                       h, ex, su, ex_graph, kc_gamma, W_ex, W_kc,
                       tgru_wih, tgru_whh, tgru_bih, tgru_bhh,
                       fpart_w, fpart_b, ulin_w, ulin_b,
                       ugru_wih, ugru_whh, ugru_bih, ugru_bhh,
                       ws, out);
}

// Round 7
// 136.244 us; speedup vs baseline: 1.8926x; 1.3402x over previous
//
#include <hip/hip_runtime.h>
#include <math.h>

#define NB  32
#define NKC 128
#define DH  64
#define NEX 1024
#define G3  192

// ws layout (floats)
#define XOFF    0          // 32*64   = 2048
#define KCIOFF  2048       // 32*128  = 4096
#define DPOFF   6144       // 32*64*128 = 262144   [b][d][i]  (TRANSPOSED)
#define FLAGOFF 268288     // 64 ints: xflag[32], done[32]
#define FLAGBYTE (FLAGOFF * 4)

// LDS union layout (floats) — identical to the verified round-1 kernel.
#define S_WHH   0       // A: tgru whh68 ch-staged ; B: fwA ; C: dpT 8448 / ul68 / wih36
#define S_WIH   6912    // A/B: tgru wih68 ; B: dptT 1088 ; C: whh36 (6912..13824)
#define S_HT    13824   // 1024
#define S_DLT   14848   // 1024
#define S_XS    15872   // 64
#define S_KRED  15936   // 512 (dedicated; C: EPS overlays)
#define S_GIS   16448   // 192
#define S_BHH3  16640   // 192
#define S_KCIL  16832   // 16
// phase C only
#define S_DPT   0       // 64*132 = 8448
#define S_UL    0       // 4352 (dpT dead)
#define S_WIH36 0       // ugru wih 6912
#define S_WHH36 6912    // ugru whh
#define S_FWB   8448    // 4352 ; later wjT 16*132 = 2112
#define S_WKT   12800   // 1088
#define S_PJS   13888   // 1024
#define S_OUTJ  14912   // 1024
#define S_EPS   15936   // 1024 (KRED/GIS/BHH3/KCIL dead in C)
#define S_NEWH  17024   // 1024 (B epilogue -> C, never aliased)
#define S_KCIF  18048   // 128
#define S_KCJ   18176   // 16
#define S_BIH   18192   // 192
#define S_BHH   18384   // 192
#define SM_SIZE 18576   // 74304 B -> same class as verified round-1 (74752)

__device__ __forceinline__ float sigf(float x) { return 1.0f / (1.0f + expf(-x)); }
__device__ __forceinline__ float dot4(float4 a, float4 b) {
    return fmaf(a.x, b.x, fmaf(a.y, b.y, fmaf(a.z, b.z, a.w * b.w)));
}

// Plain (512): r1-verified. No 2nd arg — forced caps spilled in r2/r3.
// Unroll caps (r4-verified) keep natural VGPR well under 128.
__global__ __launch_bounds__(512) void kF(
    const float* __restrict__ h, const float* __restrict__ ex,
    const float* __restrict__ su, const float* __restrict__ ex_graph,
    const float* __restrict__ kc_gamma,
    const float* __restrict__ W_ex, const float* __restrict__ W_kc,
    const float* __restrict__ tgru_wih, const float* __restrict__ tgru_whh,
    const float* __restrict__ tgru_bih, const float* __restrict__ tgru_bhh,
    const float* __restrict__ fpart_w, const float* __restrict__ fpart_b,
    const float* __restrict__ ulin_w, const float* __restrict__ ulin_b,
    const float* __restrict__ ugru_wih, const float* __restrict__ ugru_whh,
    const float* __restrict__ ugru_bih, const float* __restrict__ ugru_bhh,
    float* __restrict__ ws, float* __restrict__ out)
{
    int t = threadIdx.x, wave = t >> 6, lane = t & 63;
    int b  = blockIdx.x >> 3;
    int ck = blockIdx.x & 7;
    int i0 = ck * 16;

    __shared__ __align__(16) float sm[SM_SIZE];
    int* fx = (int*)(ws + FLAGOFF);   // x ready counters, per b (-> 8)
    int* fd = fx + 32;                // dpart/kci ready counters, per b (-> 8)

    // ---------------- Phase A: x[b][ck*8 + wave]  (1 d per wave)
    {
        float sub = su[b];
        const float* exb = ex + (size_t)b * NEX;
        int d = ck * 8 + wave;
        const float* wr = W_ex + (size_t)d * (2 * NEX);
        float a1 = 0.f, a2 = 0.f;
        for (int hh = 0; hh < 2; ++hh) {          // stream ex in 8-chunks
            float er[8];
            #pragma unroll
            for (int i = 0; i < 8; ++i) er[i] = exb[lane + (hh * 8 + i) * 64];
            #pragma unroll
            for (int i = 0; i < 8; ++i) {
                int k = lane + (hh * 8 + i) * 64;
                a1 = fmaf(er[i], wr[k], a1);
                a2 = fmaf(er[i], wr[NEX + k], a2);
            }
        }
        float v = sub * a1 + (1.0f - sub) * a2;
        #pragma unroll
        for (int off = 32; off; off >>= 1) v += __shfl_down(v, off, 64);
        if (lane == 0) ws[XOFF + b * DH + d] = v;
    }
    // EARLY tgru ch0 staging (arena 0..13824 is free in phase A; KRED is
    // dedicated at 15936) — latency hides under kci + ht staging + fx spin.
    for (int idx = t; idx < G3 * 8; idx += 512) {
        int row = idx >> 3, q = idx & 7;
        *(float4*)&sm[S_WHH + row * 36 + 4 * q] =
            *(const float4*)&tgru_whh[row * DH + 4 * q];
        *(float4*)&sm[S_WIH + row * 36 + 4 * q] =
            *(const float4*)&tgru_wih[row * DH + 4 * q];
    }
    // kci partials
    {
        int i = t & 15, ks = t >> 4, kb = ks * 32;
        const float* exb = ex + (size_t)b * NEX;
        const float* eg = ex_graph + i0 + i;
        float a = 0.f;
        #pragma unroll 4
        for (int k = 0; k < 32; ++k)
            a = fmaf(exb[kb + k], eg[(size_t)(kb + k) * NKC], a);
        sm[S_KRED + t] = a;
    }
    {
        const float* hb = h + (size_t)(b * NKC + i0) * DH;
        for (int idx = t; idx < 16 * DH; idx += 512) sm[S_HT + idx] = hb[idx];
    }
    if (t < G3) sm[S_BHH3 + t] = tgru_bhh[t];
    __syncthreads();
    if (t == 0)
        __hip_atomic_fetch_add(fx + b, 1, __ATOMIC_RELEASE, __HIP_MEMORY_SCOPE_AGENT);
    if (t < 16) {
        float s = 0.f;
        #pragma unroll
        for (int r = 0; r < 32; ++r) s += sm[S_KRED + r * 16 + t];
        sm[S_KCIL + t] = s;
        ws[KCIOFF + b * NKC + i0 + t] = s;
    }
    if (t == 0) {
        while (__hip_atomic_load(fx + b, __ATOMIC_ACQUIRE, __HIP_MEMORY_SCOPE_AGENT) < 8)
            __builtin_amdgcn_s_sleep(1);
    }
    __syncthreads();
    if (t < DH) sm[S_XS + t] = ws[XOFF + b * DH + t];
    __syncthreads();   // orders XS store (+ phase-A weight staging already fenced)

    // ---------------- tgru: ch0 compute (weights pre-staged), then ch1
    float giA = (t < G3) ? tgru_bih[t] : 0.f;
    float ar[2], az[2], an[2];
    #pragma unroll
    for (int m = 0; m < 2; ++m) {
        ar[m] = sm[S_BHH3 + lane];
        az[m] = sm[S_BHH3 + 64 + lane];
        an[m] = sm[S_BHH3 + 128 + lane];
    }
    // ch0
    if (t < G3) {
        #pragma unroll 4
        for (int q = 0; q < 8; ++q)
            giA += dot4(*(float4*)&sm[S_WIH + t * 36 + 4 * q],
                        *(float4*)&sm[S_XS + 4 * q]);
    }
    #pragma unroll 4
    for (int q = 0; q < 8; ++q) {
        float4 wr_ = *(float4*)&sm[S_WHH + lane * 36 + 4 * q];
        float4 wz_ = *(float4*)&sm[S_WHH + (64 + lane) * 36 + 4 * q];
        float4 wn_ = *(float4*)&sm[S_WHH + (128 + lane) * 36 + 4 * q];
        #pragma unroll
        for (int m = 0; m < 2; ++m) {
            float4 hk = *(float4*)&sm[S_HT + (wave * 2 + m) * DH + 4 * q];  // bcast
            ar[m] += dot4(wr_, hk);
            az[m] += dot4(wz_, hk);
            an[m] += dot4(wn_, hk);
        }
    }
    // ch1 stage
    __syncthreads();
    for (int idx = t; idx < G3 * 8; idx += 512) {
        int row = idx >> 3, q = idx & 7;
        *(float4*)&sm[S_WHH + row * 36 + 4 * q] =
            *(const float4*)&tgru_whh[row * DH + 32 + 4 * q];
        *(float4*)&sm[S_WIH + row * 36 + 4 * q] =
            *(const float4*)&tgru_wih[row * DH + 32 + 4 * q];
    }
    __syncthreads();
    // ch1
    if (t < G3) {
        #pragma unroll 4
        for (int q = 0; q < 8; ++q)
            giA += dot4(*(float4*)&sm[S_WIH + t * 36 + 4 * q],
                        *(float4*)&sm[S_XS + 32 + 4 * q]);
    }
    #pragma unroll 4
    for (int q = 0; q < 8; ++q) {
        int kb2 = 32 + 4 * q;
        float4 wr_ = *(float4*)&sm[S_WHH + lane * 36 + 4 * q];
        float4 wz_ = *(float4*)&sm[S_WHH + (64 + lane) * 36 + 4 * q];
        float4 wn_ = *(float4*)&sm[S_WHH + (128 + lane) * 36 + 4 * q];
        #pragma unroll
        for (int m = 0; m < 2; ++m) {
            float4 hk = *(float4*)&sm[S_HT + (wave * 2 + m) * DH + kb2];  // bcast
            ar[m] += dot4(wr_, hk);
            az[m] += dot4(wz_, hk);
            an[m] += dot4(wn_, hk);
        }
    }
    if (t < G3) sm[S_GIS + t] = giA;
    __syncthreads();
    // GRU epilogue per i
    #pragma unroll
    for (int m = 0; m < 2; ++m) {
        int il = wave * 2 + m;
        float hval = sm[S_HT + il * DH + lane];
        float r = sigf(sm[S_GIS + lane] + ar[m]);
        float z = sigf(sm[S_GIS + 64 + lane] + az[m]);
        float n = tanhf(sm[S_GIS + 128 + lane] + r * an[m]);
        float th = (1.0f - z) * n + z * hval;
        float kv = sm[S_KCIL + il];
        float nh = (1.0f - kv) * hval + kv * th;
        sm[S_NEWH + il * DH + lane] = nh;          // stays in LDS for phase C
        sm[S_DLT + il * DH + lane] = kv * (th - hval);
    }
    __syncthreads();
    // dpart = delta_h @ fpart_w[:, :64].T   (fwA overlays whh68 @0)
    for (int idx = t; idx < 64 * 16; idx += 512) {
        int d = idx >> 4, q = idx & 15;
        *(float4*)&sm[S_WHH + d * 68 + 4 * q] = *(const float4*)&fpart_w[d * 128 + 4 * q];
    }
    __syncthreads();
    float acc[2] = {0.f, 0.f};
    #pragma unroll 4
    for (int q = 0; q < 16; ++q) {
        float4 w = *(float4*)&sm[S_WHH + lane * 68 + 4 * q];
        #pragma unroll
        for (int m = 0; m < 2; ++m)
            acc[m] += dot4(w, *(float4*)&sm[S_DLT + (wave * 2 + m) * DH + 4 * q]);  // bcast
    }
    // transpose in LDS (stride 17, conflict-free), coalesced global write
    __syncthreads();
    #pragma unroll
    for (int m = 0; m < 2; ++m) sm[S_WIH + lane * 17 + wave * 2 + m] = acc[m];
    __syncthreads();
    for (int idx = t; idx < 1024; idx += 512) {
        int d = idx >> 4, il = idx & 15;
        ws[DPOFF + (size_t)b * 8192 + d * NKC + i0 + il] = sm[S_WIH + d * 17 + il];
    }
    __syncthreads();
    if (t == 0)
        __hip_atomic_fetch_add(fd + b, 1, __ATOMIC_RELEASE, __HIP_MEMORY_SCOPE_AGENT);

    // ---------------- Phase C: stage b-independent weights BEFORE the fd wait
    for (int idx = t; idx < 64 * 16; idx += 512) {
        int d = idx >> 4, q = idx & 15;
        *(float4*)&sm[S_FWB + d * 68 + 4 * q] =
            *(const float4*)&fpart_w[d * 128 + 64 + 4 * q];
    }
    for (int idx = t; idx < 1024; idx += 512) {
        int c = idx >> 4, jl = idx & 15;
        sm[S_WKT + jl * 68 + c] = W_kc[(size_t)c * NKC + i0 + jl];
    }
    if (t < G3) { sm[S_BIH + t] = ugru_bih[t]; sm[S_BHH + t] = ugru_bhh[t]; }
    if (t == 0) {
        while (__hip_atomic_load(fd + b, __ATOMIC_ACQUIRE, __HIP_MEMORY_SCOPE_AGENT) < 8)
            __builtin_amdgcn_s_sleep(1);
    }
    __syncthreads();
    // cross-chunk data: dpT (all d x all i of b) + kciF (all i)
    {
        const float* dp = ws + DPOFF + (size_t)b * 8192;
        #pragma unroll 4
        for (int r = 0; r < 4; ++r) {
            int idx4 = t + r * 512;
            int d = idx4 >> 5, qi = idx4 & 31;
            *(float4*)&sm[S_DPT + d * 132 + 4 * qi] = *(const float4*)&dp[d * NKC + 4 * qi];
        }
    }
    if (t < NKC) sm[S_KCIF + t] = ws[KCIOFF + b * NKC + t];
    __syncthreads();
    // epart[jl,d] = fpart_b[d] + sum_c wk[c,jl]*fpart_w[d,64+c]
    #pragma unroll
    for (int r = 0; r < 2; ++r) {
        int idx = t + r * 512;
        int jl = idx >> 6, d = idx & 63;
        float a = fpart_b[d];
        #pragma unroll 8
        for (int q = 0; q < 16; ++q)
            a += dot4(*(float4*)&sm[S_FWB + d * 68 + 4 * q],
                      *(float4*)&sm[S_WKT + jl * 68 + 4 * q]);
        sm[S_EPS + jl * DH + d] = a;
    }
    __syncthreads();   // fwB/wkT dead
    // wj transposed [jl][i], stride 132 (reuses fwB region)
    for (int idx = t; idx < 2048; idx += 512) {
        int i = idx >> 4, jl = idx & 15;
        sm[S_FWB + jl * 132 + i] = sm[S_KCIF + i] * sigf(kc_gamma[i * NKC + i0 + jl]);
    }
    __syncthreads();
    if (t < 16) {
        float s = 0.f;
        #pragma unroll 8
        for (int qi = 0; qi < 32; ++qi) {
            float4 v = *(float4*)&sm[S_FWB + t * 132 + 4 * qi];
            s += v.x + v.y + v.z + v.w;
        }
        sm[S_KCJ + t] = s;
    }
    // partj: b128 dv (own row) + b128 wj broadcast
    float ep[2], pa[2];
    #pragma unroll
    for (int m = 0; m < 2; ++m) {
        ep[m] = sm[S_EPS + (wave * 2 + m) * DH + lane];
        pa[m] = 0.f;
    }
    #pragma unroll 4
    for (int qi = 0; qi < 32; ++qi) {
        float4 dv = *(float4*)&sm[S_DPT + lane * 132 + 4 * qi];
        #pragma unroll
        for (int m = 0; m < 2; ++m) {
            float4 wv = *(float4*)&sm[S_FWB + (wave * 2 + m) * 132 + 4 * qi];  // bcast
            pa[m] = fmaf(fmaxf(dv.x + ep[m], 0.f), wv.x, pa[m]);
            pa[m] = fmaf(fmaxf(dv.y + ep[m], 0.f), wv.y, pa[m]);
            pa[m] = fmaf(fmaxf(dv.z + ep[m], 0.f), wv.z, pa[m]);
            pa[m] = fmaf(fmaxf(dv.w + ep[m], 0.f), wv.w, pa[m]);
        }
    }
    #pragma unroll
    for (int m = 0; m < 2; ++m) sm[S_PJS + (wave * 2 + m) * DH + lane] = pa[m];
    __syncthreads();
    // outj = relu(pj @ ulin_w.T + b); ul68 @0 (dpT dead)
    for (int idx = t; idx < 64 * 16; idx += 512) {
        int d = idx >> 4, q = idx & 15;
        *(float4*)&sm[S_UL + d * 68 + 4 * q] = *(const float4*)&ulin_w[d * DH + 4 * q];
    }
    float ulb = ulin_b[lane];
    __syncthreads();
    float oa[2] = {ulb, ulb};
    #pragma unroll 8
    for (int q = 0; q < 16; ++q) {
        float4 uv = *(float4*)&sm[S_UL + lane * 68 + 4 * q];
        #pragma unroll
        for (int m = 0; m < 2; ++m)
            oa[m] += dot4(uv, *(float4*)&sm[S_PJS + (wave * 2 + m) * DH + 4 * q]);  // bcast
    }
    #pragma unroll
    for (int m = 0; m < 2; ++m)
        sm[S_OUTJ + (wave * 2 + m) * DH + lane] = fmaxf(oa[m], 0.f);
    // ugru: k-chunked row-major stride-36 weights, b128 everywhere
    float gir[2], giz[2], gin[2], ghr[2], ghz[2], ghn[2];
    #pragma unroll
    for (int m = 0; m < 2; ++m)
        gir[m] = giz[m] = gin[m] = ghr[m] = ghz[m] = ghn[m] = 0.f;
    for (int ch = 0; ch < 2; ++ch) {
        __syncthreads();   // covers ul68/outjS deps
        for (int idx = t; idx < G3 * 8; idx += 512) {
            int row = idx >> 3, q = idx & 7;
            *(float4*)&sm[S_WIH36 + row * 36 + 4 * q] =
                *(const float4*)&ugru_wih[row * DH + ch * 32 + 4 * q];
            *(float4*)&sm[S_WHH36 + row * 36 + 4 * q] =
                *(const float4*)&ugru_whh[row * DH + ch * 32 + 4 * q];
        }
        __syncthreads();
        #pragma unroll 2
        for (int q = 0; q < 8; ++q) {
            int kb2 = ch * 32 + 4 * q;
            float4 wir = *(float4*)&sm[S_WIH36 + lane * 36 + 4 * q];
            float4 wiz = *(float4*)&sm[S_WIH36 + (64 + lane) * 36 + 4 * q];
            float4 win = *(float4*)&sm[S_WIH36 + (128 + lane) * 36 + 4 * q];
            float4 wwr = *(float4*)&sm[S_WHH36 + lane * 36 + 4 * q];
            float4 wwz = *(float4*)&sm[S_WHH36 + (64 + lane) * 36 + 4 * q];
            float4 wwn = *(float4*)&sm[S_WHH36 + (128 + lane) * 36 + 4 * q];
            #pragma unroll
            for (int m = 0; m < 2; ++m) {
                int jl = wave * 2 + m;
                float4 ov = *(float4*)&sm[S_OUTJ + jl * DH + kb2];   // bcast
                float4 nv = *(float4*)&sm[S_NEWH + jl * DH + kb2];   // bcast
                gir[m] += dot4(wir, ov);
                giz[m] += dot4(wiz, ov);
                gin[m] += dot4(win, ov);
                ghr[m] += dot4(wwr, nv);
                ghz[m] += dot4(wwz, nv);
                ghn[m] += dot4(wwn, nv);
            }
        }
    }
    #pragma unroll
    for (int m = 0; m < 2; ++m) {
        int jl = wave * 2 + m;
        float r = sigf(gir[m] + sm[S_BIH + lane] + ghr[m] + sm[S_BHH + lane]);
        float z = sigf(giz[m] + sm[S_BIH + 64 + lane] + ghz[m] + sm[S_BHH + 64 + lane]);
        float n = tanhf(gin[m] + sm[S_BIH + 128 + lane] +
                        r * (ghn[m] + sm[S_BHH + 128 + lane]));
        float nh = sm[S_NEWH + jl * DH + lane];
        float uh = (1.0f - z) * n + z * nh;
        float kj = sm[S_KCJ + jl];
        out[(size_t)(b * NKC + i0 + jl) * DH + lane] = (1.0f - kj) * nh + kj * uh;
    }
}

extern "C" void kernel_launch(void* const* d_in, const int* in_sizes, int n_in,
                              void* d_out, int out_size, void* d_ws, size_t ws_size,
                              hipStream_t stream) {
    const float* h        = (const float*)d_in[0];
    const float* ex       = (const float*)d_in[1];
    const float* su       = (const float*)d_in[2];
    const float* ex_graph = (const float*)d_in[3];
    const float* kc_gamma = (const float*)d_in[4];
    const float* W_ex     = (const float*)d_in[5];
    const float* W_kc     = (const float*)d_in[6];
    const float* tgru_wih = (const float*)d_in[7];
    const float* tgru_whh = (const float*)d_in[8];
    const float* tgru_bih = (const float*)d_in[9];
    const float* tgru_bhh = (const float*)d_in[10];
    const float* fpart_w  = (const float*)d_in[11];
    const float* fpart_b  = (const float*)d_in[12];
    const float* ulin_w   = (const float*)d_in[13];
    const float* ulin_b   = (const float*)d_in[14];
    const float* ugru_wih = (const float*)d_in[15];
    const float* ugru_whh = (const float*)d_in[16];
    const float* ugru_bih = (const float*)d_in[17];
    const float* ugru_bhh = (const float*)d_in[18];
    float* ws  = (float*)d_ws;
    float* out = (float*)d_out;

    // zero the per-b flag counters (workspace is poisoned between runs)
    hipMemsetAsync((char*)d_ws + FLAGBYTE, 0, 64 * sizeof(int), stream);
    hipLaunchKernelGGL(kF, dim3(256), dim3(512), 0, stream,
                       h, ex, su, ex_graph, kc_gamma, W_ex, W_kc,
                       tgru_wih, tgru_whh, tgru_bih, tgru_bhh,
                       fpart_w, fpart_b, ulin_w, ulin_b,
                       ugru_wih, ugru_whh, ugru_bih, ugru_bhh,
                       ws, out);
}

// Round 9
// 128.189 us; speedup vs baseline: 2.0115x; 1.0628x over previous
//
#include <hip/hip_runtime.h>
#include <math.h>

#define NKC 128
#define DH  64
#define NEX 1024
#define G3  192

// ws layout (floats)
#define XOFF    0         // 32*64   = 2048
#define KCIOFF  2048      // 32*128  = 4096
#define NHOFF   6144      // 32*128*64 = 262144   [b][i][d]
#define DPOFF   268288    // 32*64*128 = 262144   [b][d][i]  (TRANSPOSED)

__device__ __forceinline__ float sigf(float x) { return 1.0f / (1.0f + expf(-x)); }
__device__ __forceinline__ float dot4(float4 a, float4 b) {
    return fmaf(a.x, b.x, fmaf(a.y, b.y, fmaf(a.z, b.z, a.w * b.w)));
}

// ---------------------------------------------------------------------------
// k0: x only. 256 blocks (b x 8 d-chunks of 8) x 256 threads. (r0-verified)
// ---------------------------------------------------------------------------
__global__ __launch_bounds__(256) void k0_x(
    const float* __restrict__ ex, const float* __restrict__ su,
    const float* __restrict__ W_ex, float* __restrict__ ws)
{
    int t = threadIdx.x, wave = t >> 6, lane = t & 63;
    int b = blockIdx.x >> 3;
    int dbase = (blockIdx.x & 7) * 8;
    float sub = su[b];
    const float* exb = ex + (size_t)b * NEX;
    float er[16];
    #pragma unroll
    for (int i = 0; i < 16; ++i) er[i] = exb[lane + i * 64];
    #pragma unroll
    for (int p = 0; p < 2; ++p) {
        int d = dbase + wave * 2 + p;
        const float* wr = W_ex + (size_t)d * (2 * NEX);
        float a1 = 0.f, a2 = 0.f;
        #pragma unroll 8
        for (int i = 0; i < 16; ++i) {
            int k = lane + i * 64;
            a1 = fmaf(er[i], wr[k], a1);
            a2 = fmaf(er[i], wr[NEX + k], a2);
        }
        float v = sub * a1 + (1.0f - sub) * a2;
        #pragma unroll
        for (int off = 32; off; off >>= 1) v += __shfl_down(v, off, 64);
        if (lane == 0) ws[XOFF + b * DH + d] = v;
    }
}

// ---------------------------------------------------------------------------
// k1: kci + tgru + new_h + dpart. 256 blocks x 512 threads.
// ch0 weights prestaged in phase A (r7-verified); dpart written scattered
// (2 dwords/thread) — no LDS transpose, 2 fewer barriers.
// ---------------------------------------------------------------------------
__global__ __launch_bounds__(512) void k1_tgru(
    const float* __restrict__ h, const float* __restrict__ ex,
    const float* __restrict__ ex_graph,
    const float* __restrict__ tgru_wih, const float* __restrict__ tgru_whh,
    const float* __restrict__ tgru_bih, const float* __restrict__ tgru_bhh,
    const float* __restrict__ fpart_w, float* __restrict__ ws)
{
    int t = threadIdx.x, wave = t >> 6, lane = t & 63;
    int b = blockIdx.x >> 3;
    int i0 = (blockIdx.x & 7) * 16;

    __shared__ __align__(16) float whh68[G3 * 36];  // later: fwA (64*68)
    __shared__ __align__(16) float wih68[G3 * 36];
    __shared__ __align__(16) float ht[16 * DH];
    __shared__ __align__(16) float dlt[16 * DH];
    __shared__ __align__(16) float xs[DH];
    __shared__ float kred[512];
    __shared__ float gis[G3];
    __shared__ float bhh3[G3];
    __shared__ float kciL[16];

    // ch0 weight prestage FIRST (latency hides under kci gather + ht stage)
    for (int idx = t; idx < G3 * 8; idx += 512) {
        int row = idx >> 3, q = idx & 7;
        *(float4*)&whh68[row * 36 + 4 * q] =
            *(const float4*)&tgru_whh[row * DH + 4 * q];
        *(float4*)&wih68[row * 36 + 4 * q] =
            *(const float4*)&tgru_wih[row * DH + 4 * q];
    }
    // kci partials (longest-latency strided loads)
    {
        int i = t & 15, ks = t >> 4, kb = ks * 32;
        const float* exb = ex + (size_t)b * NEX;
        const float* eg = ex_graph + i0 + i;
        float a = 0.f;
        #pragma unroll 4
        for (int k = 0; k < 32; ++k)
            a = fmaf(exb[kb + k], eg[(size_t)(kb + k) * NKC], a);
        kred[t] = a;
    }
    if (t < 256) {
        const float* hb = h + (size_t)(b * NKC + i0) * DH;
        *(float4*)&ht[t * 4] = *(const float4*)&hb[t * 4];
    }
    if (t < DH) xs[t] = ws[XOFF + b * DH + t];     // k0 done (kernel boundary)
    if (t < G3) bhh3[t] = tgru_bhh[t];
    __syncthreads();
    if (t < 16) {
        float s = 0.f;
        #pragma unroll
        for (int r = 0; r < 32; ++r) s += kred[r * 16 + t];
        kciL[t] = s;
        ws[KCIOFF + b * NKC + i0 + t] = s;
    }

    float giA = (t < G3) ? tgru_bih[t] : 0.f;
    float ar[2], az[2], an[2];
    #pragma unroll
    for (int m = 0; m < 2; ++m) {
        ar[m] = bhh3[lane]; az[m] = bhh3[64 + lane]; an[m] = bhh3[128 + lane];
    }
    // ch0 compute (weights already resident)
    if (t < G3) {
        #pragma unroll 4
        for (int q = 0; q < 8; ++q)
            giA += dot4(*(float4*)&wih68[t * 36 + 4 * q], *(float4*)&xs[4 * q]);
    }
    #pragma unroll 4
    for (int q = 0; q < 8; ++q) {
        float4 wr_ = *(float4*)&whh68[lane * 36 + 4 * q];
        float4 wz_ = *(float4*)&whh68[(64 + lane) * 36 + 4 * q];
        float4 wn_ = *(float4*)&whh68[(128 + lane) * 36 + 4 * q];
        #pragma unroll
        for (int m = 0; m < 2; ++m) {
            float4 hk = *(float4*)&ht[(wave * 2 + m) * DH + 4 * q];   // bcast
            ar[m] += dot4(wr_, hk);
            az[m] += dot4(wz_, hk);
            an[m] += dot4(wn_, hk);
        }
    }
    __syncthreads();
    // ch1 stage
    for (int idx = t; idx < G3 * 8; idx += 512) {
        int row = idx >> 3, q = idx & 7;
        *(float4*)&whh68[row * 36 + 4 * q] =
            *(const float4*)&tgru_whh[row * DH + 32 + 4 * q];
        *(float4*)&wih68[row * 36 + 4 * q] =
            *(const float4*)&tgru_wih[row * DH + 32 + 4 * q];
    }
    __syncthreads();
    // ch1 compute
    if (t < G3) {
        #pragma unroll 4
        for (int q = 0; q < 8; ++q)
            giA += dot4(*(float4*)&wih68[t * 36 + 4 * q], *(float4*)&xs[32 + 4 * q]);
    }
    #pragma unroll 4
    for (int q = 0; q < 8; ++q) {
        int kb2 = 32 + 4 * q;
        float4 wr_ = *(float4*)&whh68[lane * 36 + 4 * q];
        float4 wz_ = *(float4*)&whh68[(64 + lane) * 36 + 4 * q];
        float4 wn_ = *(float4*)&whh68[(128 + lane) * 36 + 4 * q];
        #pragma unroll
        for (int m = 0; m < 2; ++m) {
            float4 hk = *(float4*)&ht[(wave * 2 + m) * DH + kb2];    // bcast
            ar[m] += dot4(wr_, hk);
            az[m] += dot4(wz_, hk);
            an[m] += dot4(wn_, hk);
        }
    }
    if (t < G3) gis[t] = giA;
    __syncthreads();
    // GRU epilogue per i: new_h -> ws, delta_h -> LDS
    #pragma unroll
    for (int m = 0; m < 2; ++m) {
        int il = wave * 2 + m;
        float hval = ht[il * DH + lane];
        float r = sigf(gis[lane] + ar[m]);
        float z = sigf(gis[64 + lane] + az[m]);
        float n = tanhf(gis[128 + lane] + r * an[m]);
        float th = (1.0f - z) * n + z * hval;
        float kv = kciL[il];
        float nh = (1.0f - kv) * hval + kv * th;
        ws[NHOFF + (size_t)(b * NKC + i0 + il) * DH + lane] = nh;
        dlt[il * DH + lane] = kv * (th - hval);
    }
    __syncthreads();
    // dpart = delta_h @ fpart_w[:, :64].T ; fwA overlays whh68
    float* fw68 = whh68;
    for (int idx = t; idx < 64 * 16; idx += 512) {
        int d = idx >> 4, q = idx & 15;
        *(float4*)&fw68[d * 68 + 4 * q] = *(const float4*)&fpart_w[d * 128 + 4 * q];
    }
    __syncthreads();
    float acc[2] = {0.f, 0.f};
    #pragma unroll 4
    for (int q = 0; q < 16; ++q) {
        float4 w = *(float4*)&fw68[lane * 68 + 4 * q];
        #pragma unroll
        for (int m = 0; m < 2; ++m)
            acc[m] += dot4(w, *(float4*)&dlt[(wave * 2 + m) * DH + 4 * q]);  // bcast
    }
    // direct scattered store (8 KB/block total; no transpose, no barriers)
    float* dpb = ws + DPOFF + (size_t)b * 8192 + (size_t)lane * NKC + i0;
    #pragma unroll
    for (int m = 0; m < 2; ++m) dpb[wave * 2 + m] = acc[m];
}

// ---------------------------------------------------------------------------
// kB: epart(regs) + partj(dv from global regs) + outj + kcj + ugru + h_out.
// 256 blocks x 512 threads. dpT never staged to LDS; ugru-wih-ch0 staged
// during partj; UL/FWB/WKT/newh staged at kernel start.
// ---------------------------------------------------------------------------
#define KB_FWB   0        // 64*68 = 4352   (dead after epart)
#define KB_WKT   4352     // 16*68 = 1088   (dead after epart)
#define KB_WIH36 0        // ugru wih 6912  (staged after epart barrier)
#define KB_UL    6912     // 64*68 = 4352   (dead after outj)
#define KB_PJS   11264    // 1024           (dead after outj)
#define KB_WHH36 6912     // ugru whh 6912  (staged after outj barrier)
#define KB_WJT   13824    // 16*132 = 2112
#define KB_OUTJ  15936    // 1024
#define KB_NEWH  16960    // 1024
#define KB_KCIF  17984    // 128
#define KB_KCJ   18112    // 16
#define KB_BIH   18128    // 192
#define KB_BHH   18320    // 192
#define KB_SM    18512    // 74048 B

__global__ __launch_bounds__(512) void kB_update(
    const float* __restrict__ kc_gamma, const float* __restrict__ W_kc,
    const float* __restrict__ fpart_w, const float* __restrict__ fpart_b,
    const float* __restrict__ ulin_w, const float* __restrict__ ulin_b,
    const float* __restrict__ ugru_wih, const float* __restrict__ ugru_whh,
    const float* __restrict__ ugru_bih, const float* __restrict__ ugru_bhh,
    float* __restrict__ ws, float* __restrict__ out)
{
    int t = threadIdx.x, wave = t >> 6, lane = t & 63;
    int b = blockIdx.x >> 3;
    int j0 = (blockIdx.x & 7) * 16;

    __shared__ __align__(16) float sm[KB_SM];

    // ---- stage everything start-resident (all valid: k1 completed)
    for (int idx = t; idx < 1024; idx += 512) {
        int d = idx >> 4, q = idx & 15;
        *(float4*)&sm[KB_FWB + d * 68 + 4 * q] =
            *(const float4*)&fpart_w[d * 128 + 64 + 4 * q];
        *(float4*)&sm[KB_UL + d * 68 + 4 * q] =
            *(const float4*)&ulin_w[d * DH + 4 * q];
    }
    for (int idx = t; idx < 1024; idx += 512) {
        int c = idx >> 4, jl = idx & 15;
        sm[KB_WKT + jl * 68 + c] = W_kc[(size_t)c * NKC + j0 + jl];
    }
    if (t < 256) {
        const float* nhp = ws + NHOFF + (size_t)(b * NKC + j0) * DH;
        *(float4*)&sm[KB_NEWH + t * 4] = *(const float4*)&nhp[t * 4];
    }
    if (t < NKC) sm[KB_KCIF + t] = ws[KCIOFF + b * NKC + t];
    if (t < G3) { sm[KB_BIH + t] = ugru_bih[t]; sm[KB_BHH + t] = ugru_bhh[t]; }
    float fpb = fpart_b[lane];
    float ulb = ulin_b[lane];
    __syncthreads();

    // ---- epart in REGISTERS (producer == consumer: jl = wave*2+m, d = lane)
    float epv[2];
    #pragma unroll
    for (int m = 0; m < 2; ++m) {
        float a = fpb;
        #pragma unroll 4
        for (int q = 0; q < 16; ++q)
            a += dot4(*(float4*)&sm[KB_FWB + lane * 68 + 4 * q],
                      *(float4*)&sm[KB_WKT + (wave * 2 + m) * 68 + 4 * q]);
        epv[m] = a;
    }
    // wjT [jl][i] stride 132
    for (int idx = t; idx < 2048; idx += 512) {
        int i = idx >> 4, jl = idx & 15;
        sm[KB_WJT + jl * 132 + i] =
            sm[KB_KCIF + i] * sigf(kc_gamma[(size_t)i * NKC + j0 + jl]);
    }
    __syncthreads();   // FWB/WKT dead; wjT visible
    if (t < 16) {
        float s = 0.f;
        #pragma unroll 8
        for (int qi = 0; qi < 32; ++qi) {
            float4 v = *(float4*)&sm[KB_WJT + t * 132 + 4 * qi];
            s += v.x + v.y + v.z + v.w;
        }
        sm[KB_KCJ + t] = s;
    }
    // stage ugru wih36 ch0 into W1 — loads fly during partj (T14)
    for (int idx = t; idx < G3 * 8; idx += 512) {
        int row = idx >> 3, q = idx & 7;
        *(float4*)&sm[KB_WIH36 + row * 36 + 4 * q] =
            *(const float4*)&ugru_wih[row * DH + 4 * q];
    }
    // ---- partj: dv straight from ws (lane-contiguous row, L2-resident)
    {
        const float* dprow = ws + DPOFF + (size_t)b * 8192 + (size_t)lane * NKC;
        float pa0 = 0.f, pa1 = 0.f;
        float ep0 = epv[0], ep1 = epv[1];
        #pragma unroll 8
        for (int qi = 0; qi < 32; ++qi) {
            float4 dv = *(const float4*)&dprow[4 * qi];
            float4 w0 = *(float4*)&sm[KB_WJT + (wave * 2 + 0) * 132 + 4 * qi];
            float4 w1 = *(float4*)&sm[KB_WJT + (wave * 2 + 1) * 132 + 4 * qi];
            pa0 = fmaf(fmaxf(dv.x + ep0, 0.f), w0.x, pa0);
            pa0 = fmaf(fmaxf(dv.y + ep0, 0.f), w0.y, pa0);
            pa0 = fmaf(fmaxf(dv.z + ep0, 0.f), w0.z, pa0);
            pa0 = fmaf(fmaxf(dv.w + ep0, 0.f), w0.w, pa0);
            pa1 = fmaf(fmaxf(dv.x + ep1, 0.f), w1.x, pa1);
            pa1 = fmaf(fmaxf(dv.y + ep1, 0.f), w1.y, pa1);
            pa1 = fmaf(fmaxf(dv.z + ep1, 0.f), w1.z, pa1);
            pa1 = fmaf(fmaxf(dv.w + ep1, 0.f), w1.w, pa1);
        }
        sm[KB_PJS + (wave * 2 + 0) * DH + lane] = pa0;
        sm[KB_PJS + (wave * 2 + 1) * DH + lane] = pa1;
    }
    __syncthreads();
    // ---- outj = relu(pj @ ulin_w.T + b)  (UL pre-staged)
    float oa[2] = {ulb, ulb};
    #pragma unroll 4
    for (int q = 0; q < 16; ++q) {
        float4 uv = *(float4*)&sm[KB_UL + lane * 68 + 4 * q];
        #pragma unroll
        for (int m = 0; m < 2; ++m)
            oa[m] += dot4(uv, *(float4*)&sm[KB_PJS + (wave * 2 + m) * DH + 4 * q]);
    }
    #pragma unroll
    for (int m = 0; m < 2; ++m)
        sm[KB_OUTJ + (wave * 2 + m) * DH + lane] = fmaxf(oa[m], 0.f);
    __syncthreads();   // UL/pjS dead
    // stage whh36 ch0 into W2
    for (int idx = t; idx < G3 * 8; idx += 512) {
        int row = idx >> 3, q = idx & 7;
        *(float4*)&sm[KB_WHH36 + row * 36 + 4 * q] =
            *(const float4*)&ugru_whh[row * DH + 4 * q];
    }
    __syncthreads();
    // ---- ugru: ch0 compute, ch1 stage+compute
    float gir[2], giz[2], gin[2], ghr[2], ghz[2], ghn[2];
    #pragma unroll
    for (int m = 0; m < 2; ++m)
        gir[m] = giz[m] = gin[m] = ghr[m] = ghz[m] = ghn[m] = 0.f;
    #pragma unroll 2
    for (int q = 0; q < 8; ++q) {
        int kb2 = 4 * q;
        float4 wir = *(float4*)&sm[KB_WIH36 + lane * 36 + 4 * q];
        float4 wiz = *(float4*)&sm[KB_WIH36 + (64 + lane) * 36 + 4 * q];
        float4 win = *(float4*)&sm[KB_WIH36 + (128 + lane) * 36 + 4 * q];
        float4 wwr = *(float4*)&sm[KB_WHH36 + lane * 36 + 4 * q];
        float4 wwz = *(float4*)&sm[KB_WHH36 + (64 + lane) * 36 + 4 * q];
        float4 wwn = *(float4*)&sm[KB_WHH36 + (128 + lane) * 36 + 4 * q];
        #pragma unroll
        for (int m = 0; m < 2; ++m) {
            int jl = wave * 2 + m;
            float4 ov = *(float4*)&sm[KB_OUTJ + jl * DH + kb2];   // bcast
            float4 nv = *(float4*)&sm[KB_NEWH + jl * DH + kb2];   // bcast
            gir[m] += dot4(wir, ov);
            giz[m] += dot4(wiz, ov);
            gin[m] += dot4(win, ov);
            ghr[m] += dot4(wwr, nv);
            ghz[m] += dot4(wwz, nv);
            ghn[m] += dot4(wwn, nv);
        }
    }
    __syncthreads();
    for (int idx = t; idx < G3 * 8; idx += 512) {
        int row = idx >> 3, q = idx & 7;
        *(float4*)&sm[KB_WIH36 + row * 36 + 4 * q] =
            *(const float4*)&ugru_wih[row * DH + 32 + 4 * q];
        *(float4*)&sm[KB_WHH36 + row * 36 + 4 * q] =
            *(const float4*)&ugru_whh[row * DH + 32 + 4 * q];
    }
    __syncthreads();
    #pragma unroll 2
    for (int q = 0; q < 8; ++q) {
        int kb2 = 32 + 4 * q;
        float4 wir = *(float4*)&sm[KB_WIH36 + lane * 36 + 4 * q];
        float4 wiz = *(float4*)&sm[KB_WIH36 + (64 + lane) * 36 + 4 * q];
        float4 win = *(float4*)&sm[KB_WIH36 + (128 + lane) * 36 + 4 * q];
        float4 wwr = *(float4*)&sm[KB_WHH36 + lane * 36 + 4 * q];
        float4 wwz = *(float4*)&sm[KB_WHH36 + (64 + lane) * 36 + 4 * q];
        float4 wwn = *(float4*)&sm[KB_WHH36 + (128 + lane) * 36 + 4 * q];
        #pragma unroll
        for (int m = 0; m < 2; ++m) {
            int jl = wave * 2 + m;
            float4 ov = *(float4*)&sm[KB_OUTJ + jl * DH + kb2];   // bcast
            float4 nv = *(float4*)&sm[KB_NEWH + jl * DH + kb2];   // bcast
            gir[m] += dot4(wir, ov);
            giz[m] += dot4(wiz, ov);
            gin[m] += dot4(win, ov);
            ghr[m] += dot4(wwr, nv);
            ghz[m] += dot4(wwz, nv);
            ghn[m] += dot4(wwn, nv);
        }
    }
    #pragma unroll
    for (int m = 0; m < 2; ++m) {
        int jl = wave * 2 + m;
        float r = sigf(gir[m] + sm[KB_BIH + lane] + ghr[m] + sm[KB_BHH + lane]);
        float z = sigf(giz[m] + sm[KB_BIH + 64 + lane] + ghz[m] + sm[KB_BHH + 64 + lane]);
        float n = tanhf(gin[m] + sm[KB_BIH + 128 + lane] +
                        r * (ghn[m] + sm[KB_BHH + 128 + lane]));
        float nh = sm[KB_NEWH + jl * DH + lane];
        float uh = (1.0f - z) * n + z * nh;
        float kj = sm[KB_KCJ + jl];
        out[(size_t)(b * NKC + j0 + jl) * DH + lane] = (1.0f - kj) * nh + kj * uh;
    }
}

extern "C" void kernel_launch(void* const* d_in, const int* in_sizes, int n_in,
                              void* d_out, int out_size, void* d_ws, size_t ws_size,
                              hipStream_t stream) {
    const float* h        = (const float*)d_in[0];
    const float* ex       = (const float*)d_in[1];
    const float* su       = (const float*)d_in[2];
    const float* ex_graph = (const float*)d_in[3];
    const float* kc_gamma = (const float*)d_in[4];
    const float* W_ex     = (const float*)d_in[5];
    const float* W_kc     = (const float*)d_in[6];
    const float* tgru_wih = (const float*)d_in[7];
    const float* tgru_whh = (const float*)d_in[8];
    const float* tgru_bih = (const float*)d_in[9];
    const float* tgru_bhh = (const float*)d_in[10];
    const float* fpart_w  = (const float*)d_in[11];
    const float* fpart_b  = (const float*)d_in[12];
    const float* ulin_w   = (const float*)d_in[13];
    const float* ulin_b   = (const float*)d_in[14];
    const float* ugru_wih = (const float*)d_in[15];
    const float* ugru_whh = (const float*)d_in[16];
    const float* ugru_bih = (const float*)d_in[17];
    const float* ugru_bhh = (const float*)d_in[18];
    float* ws  = (float*)d_ws;
    float* out = (float*)d_out;

    hipLaunchKernelGGL(k0_x, dim3(256), dim3(256), 0, stream,
                       ex, su, W_ex, ws);
    hipLaunchKernelGGL(k1_tgru, dim3(256), dim3(512), 0, stream,
                       h, ex, ex_graph, tgru_wih, tgru_whh, tgru_bih,
                       tgru_bhh, fpart_w, ws);
    hipLaunchKernelGGL(kB_update, dim3(256), dim3(512), 0, stream,
                       kc_gamma, W_kc, fpart_w, fpart_b, ulin_w, ulin_b,
                       ugru_wih, ugru_whh, ugru_bih, ugru_bhh, ws, out);
}